// Round 15
// baseline (129.330 us; speedup 1.0000x reference)
//
#include <hip/hip_runtime.h>
#include <cstdint>
#include <cstddef>

#define S_LEN 2048
#define DMODEL 1024
#define NHEADS 16
#define DKH 64
#define MROWS 4096
#define BH_CNT 32

typedef __bf16 bf16x8 __attribute__((ext_vector_type(8)));
typedef __bf16 bf16x2 __attribute__((ext_vector_type(2)));
typedef float f32x4 __attribute__((ext_vector_type(4)));
typedef unsigned int u32x4 __attribute__((ext_vector_type(4)));
typedef unsigned int u32;
typedef unsigned short u16;

__device__ __forceinline__ u16 f2bfu(float f) {
  u32 u = __float_as_uint(f);
  return (u16)((u + 0x7FFFu + ((u >> 16) & 1u)) >> 16);
}

__device__ __forceinline__ float bf2f(u16 v) {
  return __uint_as_float((u32)v << 16);
}

// compiler-cast bf16 pack (lowers to v_cvt_pk_bf16_f32 on gfx950)
__device__ __forceinline__ u32 pk_bf16(float a, float b) {
  bf16x2 v;
  v[0] = (__bf16)a;
  v[1] = (__bf16)b;
  return __builtin_bit_cast(u32, v);
}

// true-swap cross-lane ops (gfx950): both operands modified
__device__ __forceinline__ void pl32swap(u32& a, u32& b) {
#if __has_builtin(__builtin_amdgcn_permlane32_swap)
  auto r = __builtin_amdgcn_permlane32_swap((int)a, (int)b, false, false);
  a = (u32)r[0]; b = (u32)r[1];
#else
  asm volatile("v_permlane32_swap_b32 %0, %1" : "+v"(a), "+v"(b));
#endif
}
__device__ __forceinline__ void pl16swap(u32& a, u32& b) {
#if __has_builtin(__builtin_amdgcn_permlane16_swap)
  auto r = __builtin_amdgcn_permlane16_swap((int)a, (int)b, false, false);
  a = (u32)r[0]; b = (u32)r[1];
#else
  asm volatile("v_permlane16_swap_b32 %0, %1" : "+v"(a), "+v"(b));
#endif
}

__device__ __forceinline__ void gload16(void* lds, const void* g) {
  __builtin_amdgcn_global_load_lds(
      (const __attribute__((address_space(1))) void*)g,
      (__attribute__((address_space(3))) void*)lds, 16, 0, 0);
}

// ---------------- merged prep: x->bf16 | W^T bf16 (K pre-scaled) | Wo_eff ----------------
// blocks [0,4096): x cast; [4096,7168): W transpose; [7168,7424): Wo_eff.
// K scale folds 1/sqrt(dk)*phase AND 1/(2pi): scores arrive in REVOLUTIONS.
__global__ __launch_bounds__(256) void prep_all_k(const float* __restrict__ x,
    const float* __restrict__ Wq, const float* __restrict__ Wk,
    const float* __restrict__ Wv, const float* __restrict__ Wo,
    const float* __restrict__ ps, const float* __restrict__ ent,
    u16* __restrict__ xb, u16* __restrict__ Wb, float* __restrict__ Woeff) {
  __shared__ float tile[32][33];
  int bid = blockIdx.x;
  int t = threadIdx.x;
  if (bid < 4096) {
    int i = (bid * 256 + t) * 4;
    float4 v = *(const float4*)(x + i);
    *(uint2*)(xb + i) = make_uint2(pk_bf16(v.x, v.y), pk_bf16(v.z, v.w));
  } else if (bid < 7168) {
    int lb = bid - 4096;
    int sel = lb >> 10, rem = lb & 1023;
    int k0 = (rem & 31) * 32, c0 = (rem >> 5) * 32;
    const float* W = sel == 0 ? Wq : (sel == 1 ? Wk : Wv);
    int tx = t & 31, ty = t >> 5;
#pragma unroll
    for (int i = 0; i < 4; ++i)
      tile[ty + i * 8][tx] = W[(size_t)(k0 + ty + i * 8) * DMODEL + c0 + tx];
    __syncthreads();
#pragma unroll
    for (int i = 0; i < 4; ++i) {
      int row = ty + i * 8;
      float v = tile[tx][row];
      if (sel == 1) v *= 0.019894367886486918f * ps[(c0 + row) >> 6];  // 0.125/(2pi)
      Wb[(size_t)(sel * 1024 + c0 + row) * DMODEL + k0 + tx] = f2bfu(v);
    }
  } else {
    __shared__ float e[16];
    if (t < 16) {
      float s = 0.f;
#pragma unroll
      for (int h = 0; h < 16; ++h) s += ent[h * 16 + t];
      e[t] = s;
    }
    __syncthreads();
    int gid = (bid - 7168) * 256 + t;
    int d = gid >> 10, j = gid & 1023;
    float acc = 0.f;
#pragma unroll
    for (int m = 0; m < 16; ++m) acc += e[m] * Wo[(size_t)((m << 6) + d) * DMODEL + j];
    Woeff[(size_t)d * DMODEL + j] = acc;
  }
}

// ---------------- QKV projection GEMM: [4096,1024] x [1024,3072] ----------------
// 256x256 tile, BK=32, 8 waves (2M x 4N), double-buffered staging (64KB LDS),
// one barrier per K-step. Grid 192 = 16x12, XCD-rectangle swizzle.
// Epilogue: two 128-row passes through retired 64KB LDS -> coalesced stores.
__global__ __launch_bounds__(512, 2) void gemm_qkv_k(const u16* __restrict__ xb,
    const u16* __restrict__ Wb, u16* __restrict__ Qb, u16* __restrict__ Kb,
    u16* __restrict__ Vt) {
  __shared__ __align__(16) u16 As[2][8192];  // [dbuf][256 x 32] = 32KB
  __shared__ __align__(16) u16 Bs[2][8192];  // [dbuf][256 x 32] = 32KB
  int bid = blockIdx.x;
  int xcd = bid & 7, wi = bid >> 3;           // 24 tiles per XCD
  int mt = (xcd >> 1) * 4 + (wi & 3);         // [0,16)
  int nt = (xcd & 1) * 6 + (wi >> 2);         // [0,12)
  int m0 = mt * 256, n0 = nt * 256;
  int tid = threadIdx.x;
  int lane = tid & 63, w = tid >> 6;
  int c = lane & 15, g = lane >> 4;
  int wr = w >> 2, wcn = w & 3;               // wave: M-half x N-quarter

  // staging source addresses (pre-swizzled chunks; (r+128)&3 == r&3)
  int r2 = tid >> 2, s2 = tid & 3;
  const u16* aS = xb + (size_t)(m0 + r2) * DMODEL + ((s2 ^ (r2 & 3)) * 8);
  const u16* bS = Wb + (size_t)(n0 + r2) * DMODEL + ((s2 ^ (r2 & 3)) * 8);

  // fragment read offsets (u16 units); row&3 == c&3 for all frags
  int xorc = (g ^ (c & 3)) * 8;
  int aoff[8], boff[4];
#pragma unroll
  for (int mf = 0; mf < 8; ++mf) aoff[mf] = (wr * 128 + mf * 16 + c) * 32 + xorc;
#pragma unroll
  for (int nf = 0; nf < 4; ++nf) boff[nf] = (wcn * 64 + nf * 16 + c) * 32 + xorc;

  f32x4 acc[8][4];
#pragma unroll
  for (int i = 0; i < 8; ++i)
#pragma unroll
    for (int j = 0; j < 4; ++j) acc[i][j] = (f32x4){0.f, 0.f, 0.f, 0.f};

  auto stage = [&](int buf, int kt) {
    gload16(&As[buf][tid * 8], aS + kt);
    gload16(&As[buf][4096 + tid * 8], aS + 128 * DMODEL + kt);
    gload16(&Bs[buf][tid * 8], bS + kt);
    gload16(&Bs[buf][4096 + tid * 8], bS + 128 * DMODEL + kt);
  };
  auto compute = [&](const int off) {  // off: 0 or 8192 (compile-time literal)
    bf16x8 bfr[4];
#pragma unroll
    for (int nf = 0; nf < 4; ++nf) bfr[nf] = *(const bf16x8*)(&Bs[0][0] + off + boff[nf]);
#pragma unroll
    for (int mf = 0; mf < 8; ++mf) {
      bf16x8 af = *(const bf16x8*)(&As[0][0] + off + aoff[mf]);
#pragma unroll
      for (int nf = 0; nf < 4; ++nf)
        acc[mf][nf] = __builtin_amdgcn_mfma_f32_16x16x32_bf16(af, bfr[nf], acc[mf][nf], 0, 0, 0);
    }
  };

  stage(0, 0);
  __syncthreads();
  for (int kt = 0; kt < DMODEL; kt += 64) {
    stage(1, kt + 32);
    compute(0);
    __syncthreads();
    if (kt + 64 < DMODEL) stage(0, kt + 64);
    compute(8192);
    __syncthreads();
  }

  // ---- epilogue: two 128-row passes through retired 64KB LDS ----
  int sel = nt >> 2;            // 0:Q 1:K 2:V
  int h0 = (nt & 3) * 4;        // first of 4 heads covered
  int b = m0 >> 11, sbase = m0 & 2047;
  char* Ls = (char*)&As[0][0];
#pragma unroll
  for (int half = 0; half < 2; ++half) {
    if (wr == half) {
      if (sel == 2) {
#pragma unroll
        for (int mf = 0; mf < 8; ++mf)
#pragma unroll
          for (int nf = 0; nf < 4; ++nf) {
            int n = wcn * 64 + nf * 16 + c;
            int mh = mf * 16 + 4 * g;
            *(uint2*)(Ls + n * 256 + ((mh * 2) ^ ((n & 7) << 4))) =
                make_uint2(pk_bf16(acc[mf][nf][0], acc[mf][nf][1]),
                           pk_bf16(acc[mf][nf][2], acc[mf][nf][3]));
          }
      } else {
#pragma unroll
        for (int mf = 0; mf < 8; ++mf)
#pragma unroll
          for (int nf = 0; nf < 4; ++nf) {
            int n = wcn * 64 + nf * 16 + c;
#pragma unroll
            for (int j = 0; j < 4; ++j) {
              int mh = mf * 16 + 4 * g + j;
              __bf16 hv = (__bf16)acc[mf][nf][j];
              *(u16*)(Ls + mh * 512 + ((n * 2) ^ ((mh & 7) << 4))) =
                  __builtin_bit_cast(u16, hv);
            }
          }
      }
    }
    __syncthreads();
    if (sel == 2) {
      int n = tid >> 1, cc = tid & 1;
      int head = h0 + (n >> 6), d = n & 63;
      u16* dst = Vt + ((size_t)(b * 16 + head) * DKH + d) * S_LEN + sbase + half * 128 + cc * 64;
#pragma unroll
      for (int kk = 0; kk < 8; ++kk)
        *(uint4*)(dst + kk * 8) =
            *(const uint4*)(Ls + n * 256 + ((cc * 128 + kk * 16) ^ ((n & 7) << 4)));
    } else {
      int r = tid >> 2, cc = tid & 3;
      int head = h0 + cc;
      u16* base = (sel == 0 ? Qb : Kb);
      u16* dst = base + ((size_t)(b * 16 + head) * S_LEN + sbase + half * 128 + r) * DKH;
#pragma unroll
      for (int kk = 0; kk < 8; ++kk)
        *(uint4*)(dst + kk * 8) =
            *(const uint4*)(Ls + r * 512 + ((cc * 128 + kk * 16) ^ ((r & 7) << 4)));
    }
    __syncthreads();
  }
}

// ---------------- fused cos-softmax flash attention (q-split, 4 blocks/CU) ----------------
// 1024 blocks x 64 q-rows; 8 waves / 512 threads = (qq q-sixteenth x h k-half).
// 2-buffer shared K/V staging (33KB LDS -> 4 blocks/CU = 8 waves/SIMD for
// cross-block pipe overlap). Per-wave state halved (one 16-row q-group).
// Verified compute recipe: S^T = mfma(K,Q); in-register softmax (v_cos +
// 2 fma + v_exp2, scores in revolutions); permlane32/16 swaps move P into
// the PV B-fragment; denominator via ones-row MFMA. bf16 output.
__global__ __launch_bounds__(512) void attn_k(const u16* __restrict__ Qb,
    const u16* __restrict__ Kb, const u16* __restrict__ Vt,
    u16* __restrict__ attbufb) {
  __shared__ __align__(16) u16 Ks[2][4096];  // [dbuf][64x64] = 16KB
  __shared__ __align__(16) u16 Vs[2][4096];  // [dbuf][64x64] = 16KB
  __shared__ float dred[8][16];
  int fid = blockIdx.x;
  int swz = (fid & 7) * 128 + (fid >> 3);  // 1024 blocks, 8 XCDs -> bijective
  int bh = swz >> 5, qb = swz & 31;        // 4 heads per XCD (K/V L2-resident)
  int tid = threadIdx.x;
  int lane = tid & 63, w = tid >> 6;
  int c = lane & 15, g = lane >> 4;
  int h = w & 1, qq = w >> 1;
  int q0 = qb * 64 + qq * 16;
  const float L2E = 1.4426950408889634f;

  const u16* Kbase = Kb + (size_t)bh * S_LEN * DKH;
  const u16* Vbase = Vt + (size_t)bh * DKH * S_LEN;

  // staging: wave w stages chunk w (512 u16) of Ks and Vs (pre-swizzled src)
  int srow = w * 8 + (lane >> 3), slot = lane & 7, kp = slot ^ (srow & 7);
  const u16* kSrc = Kbase + (size_t)srow * DKH + kp * 8;
  const u16* vSrc = Vbase + (size_t)srow * S_LEN + kp * 8;
  auto stage = [&](int buf, int tile) {
    gload16(&Ks[buf][w * 512], kSrc + (size_t)tile * 64 * DKH);
    gload16(&Vs[buf][w * 512], vSrc + tile * 64);
  };

  int rot = qb;       // rotated k-start spreads L2 sets across a head's blocks
  stage(0, rot & 31); // prologue

  bf16x8 qf[2];  // [dk-half]
  {
    const u16* qp = Qb + ((size_t)bh * S_LEN + q0 + c) * DKH + g * 8;
    qf[0] = *(const bf16x8*)qp;
    qf[1] = *(const bf16x8*)(qp + 32);
  }
  bf16x8 onesf;
#pragma unroll
  for (int i = 0; i < 8; ++i) onesf[i] = (__bf16)1.0f;

  // precomputed LDS fragment pointers (buf0); buf1 = +4096 u16 (compile-time)
  const u16* kptr[2][2];  // [fm][dk-half]
#pragma unroll
  for (int fm = 0; fm < 2; ++fm) {
    int row = h * 32 + fm * 16 + c;
    kptr[fm][0] = &Ks[0][row * 64 + ((g ^ (row & 7)) * 8)];
    kptr[fm][1] = &Ks[0][row * 64 + (((4 + g) ^ (row & 7)) * 8)];
  }
  const u16* vptr[4];  // [fd]
#pragma unroll
  for (int fd = 0; fd < 4; ++fd) {
    int vrow = fd * 16 + c;
    vptr[fd] = &Vs[0][vrow * 64 + (((4 * h + g) ^ (vrow & 7)) * 8)];
  }

  f32x4 attT[4];  // [fd]
#pragma unroll
  for (int i = 0; i < 4; ++i) attT[i] = (f32x4){0.f, 0.f, 0.f, 0.f};
  f32x4 denacc = (f32x4){0.f, 0.f, 0.f, 0.f};

  auto compute = [&](const int off) {  // off: 0 or 4096 (compile-time literal)
    f32x4 sT[2];  // [fm]
    __builtin_amdgcn_s_setprio(1);
#pragma unroll
    for (int fm = 0; fm < 2; ++fm) {
      bf16x8 a0 = *(const bf16x8*)(kptr[fm][0] + off);
      bf16x8 a1 = *(const bf16x8*)(kptr[fm][1] + off);
      f32x4 z = (f32x4){0.f, 0.f, 0.f, 0.f};
      z = __builtin_amdgcn_mfma_f32_16x16x32_bf16(a0, qf[0], z, 0, 0, 0);
      sT[fm] = __builtin_amdgcn_mfma_f32_16x16x32_bf16(a1, qf[1], z, 0, 0, 0);
    }
    __builtin_amdgcn_s_setprio(0);
    u32 wq[2][2];  // [fm][r]
#pragma unroll
    for (int fm = 0; fm < 2; ++fm) {
      float pv[4];
#pragma unroll
      for (int j = 0; j < 4; ++j) {
        float cv = __builtin_amdgcn_cosf(sT[fm][j]);  // revolutions
        float w2 = __fmaf_rn(cv, __fmaf_rn(0.2f * L2E, cv, L2E), -0.1f * L2E);
        pv[j] = __builtin_amdgcn_exp2f(w2);
      }
      wq[fm][0] = pk_bf16(pv[0], pv[1]);
      wq[fm][1] = pk_bf16(pv[2], pv[3]);
    }
    u32 b0 = wq[0][0], b2 = wq[1][0];
    pl32swap(b0, b2);
    pl16swap(b0, b2);
    u32 b1 = wq[0][1], b3 = wq[1][1];
    pl32swap(b1, b3);
    pl16swap(b1, b3);
    bf16x8 pf = __builtin_bit_cast(bf16x8, (u32x4){b0, b1, b2, b3});
    __builtin_amdgcn_s_setprio(1);
#pragma unroll
    for (int fd = 0; fd < 4; ++fd) {
      bf16x8 vf = *(const bf16x8*)(vptr[fd] + off);
      attT[fd] = __builtin_amdgcn_mfma_f32_16x16x32_bf16(vf, pf, attT[fd], 0, 0, 0);
    }
    denacc = __builtin_amdgcn_mfma_f32_16x16x32_bf16(onesf, pf, denacc, 0, 0, 0);
    __builtin_amdgcn_s_setprio(0);
  };

  __syncthreads();
  for (int t = 0; t < 32; t += 2) {
    stage(1, (t + 1 + rot) & 31);
    compute(0);
    __syncthreads();
    if (t + 2 < 32) stage(0, (t + 2 + rot) & 31);
    compute(4096);
    __syncthreads();
  }

  // ---- epilogue: combine h-partners (waves w and w^1 share q-rows) ----
  if (g == 0) dred[w][c] = denacc[0];
  float* Rq = (float*)&Ks[0][0] + qq * 1024;  // 4 disjoint 4KB regions
  if (h == 1) {
#pragma unroll
    for (int fd = 0; fd < 4; ++fd)
      *(f32x4*)&Rq[c * 64 + fd * 16 + 4 * g] = attT[fd];
  }
  __syncthreads();
  if (h == 0) {
    float inv = 1.f / (dred[w][c] + dred[w ^ 1][c]);
#pragma unroll
    for (int fd = 0; fd < 4; ++fd) {
      f32x4 part = *(const f32x4*)&Rq[c * 64 + fd * 16 + 4 * g];
      f32x4 tot = (attT[fd] + part) * inv;
      int q = q0 + c;
      *(uint2*)(attbufb + ((size_t)bh * S_LEN + q) * DKH + fd * 16 + 4 * g) =
          make_uint2(pk_bf16(tot[0], tot[1]), pk_bf16(tot[2], tot[3]));
    }
  }
}

// ---------------- head-reduce + a@Wo_eff + bias + residual + LayerNorm ----------------
__global__ __launch_bounds__(256) void fuse_out_ln_k(const u16* __restrict__ attbufb,
    const float* __restrict__ Woeff, const float* __restrict__ bo,
    const float* __restrict__ x, const float* __restrict__ gamma,
    const float* __restrict__ beta, float* __restrict__ out) {
  __shared__ float red[8][256];
  __shared__ __align__(16) float a[8][64];
  __shared__ float sred[8][4][2];
  int t = threadIdx.x;
  int r0 = blockIdx.x * 8;
  int d = t & 63, hg = t >> 6;
#pragma unroll
  for (int rr = 0; rr < 8; ++rr) {
    int m = r0 + rr, b = m >> 11, sr = m & 2047;
    float pa = 0.f;
#pragma unroll
    for (int hh = 0; hh < 4; ++hh) {
      int h = hg * 4 + hh;
      pa += bf2f(attbufb[(((size_t)(b * 16 + h)) * S_LEN + sr) * DKH + d]);
    }
    red[rr][t] = pa;
  }
  __syncthreads();
#pragma unroll
  for (int e = 0; e < 2; ++e) {
    int idx = t + e * 256;
    int rr = idx >> 6, dd = idx & 63;
    a[rr][dd] = red[rr][dd] + red[rr][64 + dd] + red[rr][128 + dd] + red[rr][192 + dd];
  }
  __syncthreads();

  float o[8][4];
#pragma unroll
  for (int rr = 0; rr < 8; ++rr) { o[rr][0] = o[rr][1] = o[rr][2] = o[rr][3] = 0.f; }
  int c4 = t * 4;
  for (int dd = 0; dd < 64; dd += 4) {
    float4 wv0 = *(const float4*)(Woeff + (size_t)(dd + 0) * DMODEL + c4);
    float4 wv1 = *(const float4*)(Woeff + (size_t)(dd + 1) * DMODEL + c4);
    float4 wv2 = *(const float4*)(Woeff + (size_t)(dd + 2) * DMODEL + c4);
    float4 wv3 = *(const float4*)(Woeff + (size_t)(dd + 3) * DMODEL + c4);
#pragma unroll
    for (int rr = 0; rr < 8; ++rr) {
      float4 av = *(const float4*)&a[rr][dd];
      o[rr][0] += av.x * wv0.x + av.y * wv1.x + av.z * wv2.x + av.w * wv3.x;
      o[rr][1] += av.x * wv0.y + av.y * wv1.y + av.z * wv2.y + av.w * wv3.y;
      o[rr][2] += av.x * wv0.z + av.y * wv1.z + av.z * wv2.z + av.w * wv3.z;
      o[rr][3] += av.x * wv0.w + av.y * wv1.w + av.z * wv2.w + av.w * wv3.w;
    }
  }
  float4 bv = *(const float4*)(bo + c4);
  int w = t >> 6, lane = t & 63;
#pragma unroll
  for (int rr = 0; rr < 8; ++rr) {
    int m = r0 + rr;
    float4 xv = *(const float4*)(x + (size_t)m * DMODEL + c4);
    o[rr][0] += bv.x + xv.x;
    o[rr][1] += bv.y + xv.y;
    o[rr][2] += bv.z + xv.z;
    o[rr][3] += bv.w + xv.w;
    float s = o[rr][0] + o[rr][1] + o[rr][2] + o[rr][3];
    float q = o[rr][0] * o[rr][0] + o[rr][1] * o[rr][1] + o[rr][2] * o[rr][2] + o[rr][3] * o[rr][3];
#pragma unroll
    for (int mm = 1; mm < 64; mm <<= 1) {
      s += __shfl_xor(s, mm, 64);
      q += __shfl_xor(q, mm, 64);
    }
    if (lane == 0) { sred[rr][w][0] = s; sred[rr][w][1] = q; }
  }
  __syncthreads();
  float4 gv = *(const float4*)(gamma + c4);
  float4 bev = *(const float4*)(beta + c4);
#pragma unroll
  for (int rr = 0; rr < 8; ++rr) {
    float s = sred[rr][0][0] + sred[rr][1][0] + sred[rr][2][0] + sred[rr][3][0];
    float q = sred[rr][0][1] + sred[rr][1][1] + sred[rr][2][1] + sred[rr][3][1];
    float mu = s * (1.f / 1024.f);
    float var = q * (1.f / 1024.f) - mu * mu;
    float rs = rsqrtf(var + 1e-6f);
    int m = r0 + rr;
    float4 ov;
    ov.x = gv.x * (o[rr][0] - mu) * rs + bev.x;
    ov.y = gv.y * (o[rr][1] - mu) * rs + bev.y;
    ov.z = gv.z * (o[rr][2] - mu) * rs + bev.z;
    ov.w = gv.w * (o[rr][3] - mu) * rs + bev.w;
    *(float4*)(out + (size_t)m * DMODEL + c4) = ov;
  }
}

extern "C" void kernel_launch(void* const* d_in, const int* in_sizes, int n_in,
                              void* d_out, int out_size, void* d_ws, size_t ws_size,
                              hipStream_t stream) {
  const float* x = (const float*)d_in[0];
  const float* Wq = (const float*)d_in[1];
  const float* Wk = (const float*)d_in[2];
  const float* Wv = (const float*)d_in[3];
  const float* Wo = (const float*)d_in[4];
  const float* bo = (const float*)d_in[5];
  const float* ps = (const float*)d_in[6];
  const float* ent = (const float*)d_in[7];
  const float* gamma = (const float*)d_in[8];
  const float* beta = (const float*)d_in[9];
  float* out = (float*)d_out;

  char* ws = (char*)d_ws;
  size_t o = 0;
  u16* xb = (u16*)(ws + o);    o += (size_t)MROWS * DMODEL * 2;        // 8 MB
  u16* Wb = (u16*)(ws + o);    o += (size_t)3072 * 1024 * 2;           // 6 MB
  u16* Qb = (u16*)(ws + o);    o += (size_t)BH_CNT * S_LEN * DKH * 2;  // 8 MB
  u16* Kb = (u16*)(ws + o);    o += (size_t)BH_CNT * S_LEN * DKH * 2;  // 8 MB
  u16* Vt = (u16*)(ws + o);    o += (size_t)BH_CNT * S_LEN * DKH * 2;  // 8 MB
  float* Woeff = (float*)(ws + o);   o += (size_t)DKH * DMODEL * 4;    // 256 KB
  u16* attbufb = (u16*)(ws + o);     o += (size_t)BH_CNT * S_LEN * DKH * 2;  // 8 MB

  prep_all_k<<<dim3(7424), dim3(256), 0, stream>>>(x, Wq, Wk, Wv, Wo, ps, ent,
                                                   xb, Wb, Woeff);
  gemm_qkv_k<<<dim3(192), dim3(512), 0, stream>>>(xb, Wb, Qb, Kb, Vt);
  attn_k<<<dim3(1024), dim3(512), 0, stream>>>(Qb, Kb, Vt, attbufb);
  fuse_out_ln_k<<<dim3(512), dim3(256), 0, stream>>>(attbufb, Woeff, bo, x, gamma, beta, out);
}

// Round 16
// 127.059 us; speedup vs baseline: 1.0179x; 1.0179x over previous
//
#include <hip/hip_runtime.h>
#include <cstdint>
#include <cstddef>

#define S_LEN 2048
#define DMODEL 1024
#define NHEADS 16
#define DKH 64
#define MROWS 4096
#define BH_CNT 32

typedef __bf16 bf16x8 __attribute__((ext_vector_type(8)));
typedef __bf16 bf16x2 __attribute__((ext_vector_type(2)));
typedef float f32x4 __attribute__((ext_vector_type(4)));
typedef unsigned int u32x4 __attribute__((ext_vector_type(4)));
typedef unsigned int u32;
typedef unsigned short u16;

__device__ __forceinline__ u16 f2bfu(float f) {
  u32 u = __float_as_uint(f);
  return (u16)((u + 0x7FFFu + ((u >> 16) & 1u)) >> 16);
}

__device__ __forceinline__ float bf2f(u16 v) {
  return __uint_as_float((u32)v << 16);
}

// compiler-cast bf16 pack (lowers to v_cvt_pk_bf16_f32 on gfx950)
__device__ __forceinline__ u32 pk_bf16(float a, float b) {
  bf16x2 v;
  v[0] = (__bf16)a;
  v[1] = (__bf16)b;
  return __builtin_bit_cast(u32, v);
}

// true-swap cross-lane ops (gfx950): both operands modified
__device__ __forceinline__ void pl32swap(u32& a, u32& b) {
#if __has_builtin(__builtin_amdgcn_permlane32_swap)
  auto r = __builtin_amdgcn_permlane32_swap((int)a, (int)b, false, false);
  a = (u32)r[0]; b = (u32)r[1];
#else
  asm volatile("v_permlane32_swap_b32 %0, %1" : "+v"(a), "+v"(b));
#endif
}
__device__ __forceinline__ void pl16swap(u32& a, u32& b) {
#if __has_builtin(__builtin_amdgcn_permlane16_swap)
  auto r = __builtin_amdgcn_permlane16_swap((int)a, (int)b, false, false);
  a = (u32)r[0]; b = (u32)r[1];
#else
  asm volatile("v_permlane16_swap_b32 %0, %1" : "+v"(a), "+v"(b));
#endif
}

__device__ __forceinline__ void gload16(void* lds, const void* g) {
  __builtin_amdgcn_global_load_lds(
      (const __attribute__((address_space(1))) void*)g,
      (__attribute__((address_space(3))) void*)lds, 16, 0, 0);
}

// wave-local counted wait on outstanding global loads (rule #18: fence after)
#define WAITV(n)                                            \
  do {                                                      \
    asm volatile("s_waitcnt vmcnt(" #n ")" ::: "memory");   \
    __builtin_amdgcn_sched_barrier(0);                      \
  } while (0)

// ---------------- merged prep: x->bf16 | W^T bf16 (K pre-scaled) | Wo_eff ----------------
// blocks [0,4096): x cast; [4096,7168): W transpose; [7168,7424): Wo_eff.
// K scale folds 1/sqrt(dk)*phase AND 1/(2pi): scores arrive in REVOLUTIONS.
__global__ __launch_bounds__(256) void prep_all_k(const float* __restrict__ x,
    const float* __restrict__ Wq, const float* __restrict__ Wk,
    const float* __restrict__ Wv, const float* __restrict__ Wo,
    const float* __restrict__ ps, const float* __restrict__ ent,
    u16* __restrict__ xb, u16* __restrict__ Wb, float* __restrict__ Woeff) {
  __shared__ float tile[32][33];
  int bid = blockIdx.x;
  int t = threadIdx.x;
  if (bid < 4096) {
    int i = (bid * 256 + t) * 4;
    float4 v = *(const float4*)(x + i);
    *(uint2*)(xb + i) = make_uint2(pk_bf16(v.x, v.y), pk_bf16(v.z, v.w));
  } else if (bid < 7168) {
    int lb = bid - 4096;
    int sel = lb >> 10, rem = lb & 1023;
    int k0 = (rem & 31) * 32, c0 = (rem >> 5) * 32;
    const float* W = sel == 0 ? Wq : (sel == 1 ? Wk : Wv);
    int tx = t & 31, ty = t >> 5;
#pragma unroll
    for (int i = 0; i < 4; ++i)
      tile[ty + i * 8][tx] = W[(size_t)(k0 + ty + i * 8) * DMODEL + c0 + tx];
    __syncthreads();
#pragma unroll
    for (int i = 0; i < 4; ++i) {
      int row = ty + i * 8;
      float v = tile[tx][row];
      if (sel == 1) v *= 0.019894367886486918f * ps[(c0 + row) >> 6];  // 0.125/(2pi)
      Wb[(size_t)(sel * 1024 + c0 + row) * DMODEL + k0 + tx] = f2bfu(v);
    }
  } else {
    __shared__ float e[16];
    if (t < 16) {
      float s = 0.f;
#pragma unroll
      for (int h = 0; h < 16; ++h) s += ent[h * 16 + t];
      e[t] = s;
    }
    __syncthreads();
    int gid = (bid - 7168) * 256 + t;
    int d = gid >> 10, j = gid & 1023;
    float acc = 0.f;
#pragma unroll
    for (int m = 0; m < 16; ++m) acc += e[m] * Wo[(size_t)((m << 6) + d) * DMODEL + j];
    Woeff[(size_t)d * DMODEL + j] = acc;
  }
}

// ---------------- QKV projection GEMM: [4096,1024] x [1024,3072] ----------------
// 256x256 tile, BK=32, 8 waves (2M x 4N), double-buffered staging (64KB LDS),
// one barrier per K-step. Grid 192 = 16x12, XCD-rectangle swizzle.
// Epilogue: two 128-row passes through retired 64KB LDS -> coalesced stores.
__global__ __launch_bounds__(512, 2) void gemm_qkv_k(const u16* __restrict__ xb,
    const u16* __restrict__ Wb, u16* __restrict__ Qb, u16* __restrict__ Kb,
    u16* __restrict__ Vt) {
  __shared__ __align__(16) u16 As[2][8192];  // [dbuf][256 x 32] = 32KB
  __shared__ __align__(16) u16 Bs[2][8192];  // [dbuf][256 x 32] = 32KB
  int bid = blockIdx.x;
  int xcd = bid & 7, wi = bid >> 3;           // 24 tiles per XCD
  int mt = (xcd >> 1) * 4 + (wi & 3);         // [0,16)
  int nt = (xcd & 1) * 6 + (wi >> 2);         // [0,12)
  int m0 = mt * 256, n0 = nt * 256;
  int tid = threadIdx.x;
  int lane = tid & 63, w = tid >> 6;
  int c = lane & 15, g = lane >> 4;
  int wr = w >> 2, wcn = w & 3;               // wave: M-half x N-quarter

  // staging source addresses (pre-swizzled chunks; (r+128)&3 == r&3)
  int r2 = tid >> 2, s2 = tid & 3;
  const u16* aS = xb + (size_t)(m0 + r2) * DMODEL + ((s2 ^ (r2 & 3)) * 8);
  const u16* bS = Wb + (size_t)(n0 + r2) * DMODEL + ((s2 ^ (r2 & 3)) * 8);

  // fragment read offsets (u16 units); row&3 == c&3 for all frags
  int xorc = (g ^ (c & 3)) * 8;
  int aoff[8], boff[4];
#pragma unroll
  for (int mf = 0; mf < 8; ++mf) aoff[mf] = (wr * 128 + mf * 16 + c) * 32 + xorc;
#pragma unroll
  for (int nf = 0; nf < 4; ++nf) boff[nf] = (wcn * 64 + nf * 16 + c) * 32 + xorc;

  f32x4 acc[8][4];
#pragma unroll
  for (int i = 0; i < 8; ++i)
#pragma unroll
    for (int j = 0; j < 4; ++j) acc[i][j] = (f32x4){0.f, 0.f, 0.f, 0.f};

  auto stage = [&](int buf, int kt) {
    gload16(&As[buf][tid * 8], aS + kt);
    gload16(&As[buf][4096 + tid * 8], aS + 128 * DMODEL + kt);
    gload16(&Bs[buf][tid * 8], bS + kt);
    gload16(&Bs[buf][4096 + tid * 8], bS + 128 * DMODEL + kt);
  };
  auto compute = [&](const int off) {  // off: 0 or 8192 (compile-time literal)
    bf16x8 bfr[4];
#pragma unroll
    for (int nf = 0; nf < 4; ++nf) bfr[nf] = *(const bf16x8*)(&Bs[0][0] + off + boff[nf]);
#pragma unroll
    for (int mf = 0; mf < 8; ++mf) {
      bf16x8 af = *(const bf16x8*)(&As[0][0] + off + aoff[mf]);
#pragma unroll
      for (int nf = 0; nf < 4; ++nf)
        acc[mf][nf] = __builtin_amdgcn_mfma_f32_16x16x32_bf16(af, bfr[nf], acc[mf][nf], 0, 0, 0);
    }
  };

  stage(0, 0);
  __syncthreads();
  for (int kt = 0; kt < DMODEL; kt += 64) {
    stage(1, kt + 32);
    compute(0);
    __syncthreads();
    if (kt + 64 < DMODEL) stage(0, kt + 64);
    compute(8192);
    __syncthreads();
  }

  // ---- epilogue: two 128-row passes through retired 64KB LDS ----
  int sel = nt >> 2;            // 0:Q 1:K 2:V
  int h0 = (nt & 3) * 4;        // first of 4 heads covered
  int b = m0 >> 11, sbase = m0 & 2047;
  char* Ls = (char*)&As[0][0];
#pragma unroll
  for (int half = 0; half < 2; ++half) {
    if (wr == half) {
      if (sel == 2) {
#pragma unroll
        for (int mf = 0; mf < 8; ++mf)
#pragma unroll
          for (int nf = 0; nf < 4; ++nf) {
            int n = wcn * 64 + nf * 16 + c;
            int mh = mf * 16 + 4 * g;
            *(uint2*)(Ls + n * 256 + ((mh * 2) ^ ((n & 7) << 4))) =
                make_uint2(pk_bf16(acc[mf][nf][0], acc[mf][nf][1]),
                           pk_bf16(acc[mf][nf][2], acc[mf][nf][3]));
          }
      } else {
#pragma unroll
        for (int mf = 0; mf < 8; ++mf)
#pragma unroll
          for (int nf = 0; nf < 4; ++nf) {
            int n = wcn * 64 + nf * 16 + c;
#pragma unroll
            for (int j = 0; j < 4; ++j) {
              int mh = mf * 16 + 4 * g + j;
              __bf16 hv = (__bf16)acc[mf][nf][j];
              *(u16*)(Ls + mh * 512 + ((n * 2) ^ ((mh & 7) << 4))) =
                  __builtin_bit_cast(u16, hv);
            }
          }
      }
    }
    __syncthreads();
    if (sel == 2) {
      int n = tid >> 1, cc = tid & 1;
      int head = h0 + (n >> 6), d = n & 63;
      u16* dst = Vt + ((size_t)(b * 16 + head) * DKH + d) * S_LEN + sbase + half * 128 + cc * 64;
#pragma unroll
      for (int kk = 0; kk < 8; ++kk)
        *(uint4*)(dst + kk * 8) =
            *(const uint4*)(Ls + n * 256 + ((cc * 128 + kk * 16) ^ ((n & 7) << 4)));
    } else {
      int r = tid >> 2, cc = tid & 3;
      int head = h0 + cc;
      u16* base = (sel == 0 ? Qb : Kb);
      u16* dst = base + ((size_t)(b * 16 + head) * S_LEN + sbase + half * 128 + r) * DKH;
#pragma unroll
      for (int kk = 0; kk < 8; ++kk)
        *(uint4*)(dst + kk * 8) =
            *(const uint4*)(Ls + r * 512 + ((cc * 128 + kk * 16) ^ ((r & 7) << 4)));
    }
    __syncthreads();
  }
}

// ---------------- fused cos-softmax flash attention ----------------
// 8 waves / 512 threads (grp x h x qh), one shared staged K/V tile per block.
// QUAD-buffered staging with T4 counted-vmcnt raw barriers: per 2 tiles --
// compute pair -> release s_barrier -> stage(t+4,t+5) -> vmcnt(4) (proves
// t+2,t+3 landed; leaves t+4,t+5 in flight ACROSS the barrier) -> ready
// s_barrier. No full vmcnt(0) drains in steady state. Compute recipe verified
// since round 7: S^T = mfma(K,Q); in-register softmax (v_cos + 2 fma +
// v_exp2, scores in revolutions); permlane32/16 swaps move P into the PV
// B-fragment; denominator via ones-row MFMA. Output written as bf16.
__global__ __launch_bounds__(512) void attn_k(const u16* __restrict__ Qb,
    const u16* __restrict__ Kb, const u16* __restrict__ Vt,
    u16* __restrict__ attbufb) {
  __shared__ __align__(16) u16 Ks[4][4096];  // [4buf][64x64] = 32KB
  __shared__ __align__(16) u16 Vs[4][4096];  // [4buf][64x64] = 32KB
  __shared__ float dred[8][2][16];
  int fid = blockIdx.x;
  int swz = (fid & 7) * 64 + (fid >> 3);  // 512 blocks, 8 XCDs -> bijective
  int bh = swz >> 4, qb = swz & 15;       // 4 heads per XCD (K/V 2MB L2-resident)
  int tid = threadIdx.x;
  int lane = tid & 63, w = tid >> 6;
  int c = lane & 15, g = lane >> 4;
  int grp = w >> 2, h = (w >> 1) & 1, qh = w & 1;
  int q0 = qb * 128 + grp * 64;
  const float L2E = 1.4426950408889634f;

  // Q fragments FIRST (older than staging loads -> drained by first vmcnt(4))
  bf16x8 qf[2][2];  // [qg][dk-half]
#pragma unroll
  for (int qg = 0; qg < 2; ++qg) {
    const u16* qp = Qb + ((size_t)bh * S_LEN + q0 + qh * 32 + qg * 16 + c) * DKH + g * 8;
    qf[qg][0] = *(const bf16x8*)qp;
    qf[qg][1] = *(const bf16x8*)(qp + 32);
  }

  const u16* Kbase = Kb + (size_t)bh * S_LEN * DKH;
  const u16* Vbase = Vt + (size_t)bh * DKH * S_LEN;

  // staging: wave w stages chunk w (512 u16) of Ks and Vs (pre-swizzled src)
  int srow = w * 8 + (lane >> 3), slot = lane & 7, kp = slot ^ (srow & 7);
  const u16* kSrc = Kbase + (size_t)srow * DKH + kp * 8;
  const u16* vSrc = Vbase + (size_t)srow * S_LEN + kp * 8;
  auto stage = [&](int buf, int tile) {
    gload16(&Ks[buf][w * 512], kSrc + (size_t)tile * 64 * DKH);
    gload16(&Vs[buf][w * 512], vSrc + tile * 64);
  };

  int rot = qb * 2;  // rotated k-start spreads L2 sets across a head's blocks
  stage(0, rot & 31);
  stage(1, (rot + 1) & 31);
  stage(2, (rot + 2) & 31);
  stage(3, (rot + 3) & 31);

  bf16x8 onesf;
#pragma unroll
  for (int i = 0; i < 8; ++i) onesf[i] = (__bf16)1.0f;

  // precomputed LDS fragment pointers (buf0); bufN = +N*4096 u16 (compile-time)
  const u16* kptr[2][2];  // [fm][dk-half]
#pragma unroll
  for (int fm = 0; fm < 2; ++fm) {
    int row = h * 32 + fm * 16 + c;
    kptr[fm][0] = &Ks[0][row * 64 + ((g ^ (row & 7)) * 8)];
    kptr[fm][1] = &Ks[0][row * 64 + (((4 + g) ^ (row & 7)) * 8)];
  }
  const u16* vptr[4];  // [fd]
#pragma unroll
  for (int fd = 0; fd < 4; ++fd) {
    int vrow = fd * 16 + c;
    vptr[fd] = &Vs[0][vrow * 64 + (((4 * h + g) ^ (vrow & 7)) * 8)];
  }

  f32x4 attT[4][2];  // [fd][qg]
#pragma unroll
  for (int i = 0; i < 4; ++i)
#pragma unroll
    for (int qg = 0; qg < 2; ++qg) attT[i][qg] = (f32x4){0.f, 0.f, 0.f, 0.f};
  f32x4 denacc[2];
  denacc[0] = (f32x4){0.f, 0.f, 0.f, 0.f};
  denacc[1] = (f32x4){0.f, 0.f, 0.f, 0.f};

  auto compute = [&](const int off) {  // off: buf*4096 (compile-time literal)
    f32x4 sT[2][2];  // [fm][qg]
    __builtin_amdgcn_s_setprio(1);
#pragma unroll
    for (int fm = 0; fm < 2; ++fm) {
      bf16x8 a0 = *(const bf16x8*)(kptr[fm][0] + off);
      bf16x8 a1 = *(const bf16x8*)(kptr[fm][1] + off);
#pragma unroll
      for (int qg = 0; qg < 2; ++qg) {
        f32x4 z = (f32x4){0.f, 0.f, 0.f, 0.f};
        z = __builtin_amdgcn_mfma_f32_16x16x32_bf16(a0, qf[qg][0], z, 0, 0, 0);
        sT[fm][qg] = __builtin_amdgcn_mfma_f32_16x16x32_bf16(a1, qf[qg][1], z, 0, 0, 0);
      }
    }
    __builtin_amdgcn_s_setprio(0);
    u32 wq[2][2][2];  // [qg][fm][r]
#pragma unroll
    for (int fm = 0; fm < 2; ++fm)
#pragma unroll
      for (int qg = 0; qg < 2; ++qg) {
        float pv[4];
#pragma unroll
        for (int j = 0; j < 4; ++j) {
          float cv = __builtin_amdgcn_cosf(sT[fm][qg][j]);  // revolutions
          float w2 = __fmaf_rn(cv, __fmaf_rn(0.2f * L2E, cv, L2E), -0.1f * L2E);
          pv[j] = __builtin_amdgcn_exp2f(w2);
        }
        wq[qg][fm][0] = pk_bf16(pv[0], pv[1]);
        wq[qg][fm][1] = pk_bf16(pv[2], pv[3]);
      }
    bf16x8 pf[2];
#pragma unroll
    for (int qg = 0; qg < 2; ++qg) {
      u32 b0 = wq[qg][0][0], b2 = wq[qg][1][0];
      pl32swap(b0, b2);
      pl16swap(b0, b2);
      u32 b1 = wq[qg][0][1], b3 = wq[qg][1][1];
      pl32swap(b1, b3);
      pl16swap(b1, b3);
      pf[qg] = __builtin_bit_cast(bf16x8, (u32x4){b0, b1, b2, b3});
    }
    __builtin_amdgcn_s_setprio(1);
#pragma unroll
    for (int fd = 0; fd < 4; ++fd) {
      bf16x8 vf = *(const bf16x8*)(vptr[fd] + off);
#pragma unroll
      for (int qg = 0; qg < 2; ++qg)
        attT[fd][qg] = __builtin_amdgcn_mfma_f32_16x16x32_bf16(vf, pf[qg], attT[fd][qg], 0, 0, 0);
    }
#pragma unroll
    for (int qg = 0; qg < 2; ++qg)
      denacc[qg] = __builtin_amdgcn_mfma_f32_16x16x32_bf16(onesf, pf[qg], denacc[qg], 0, 0, 0);
    __builtin_amdgcn_s_setprio(0);
  };

  // prologue: tiles 0,1 proven resident; tiles 2,3 in flight
  WAITV(4);
  __builtin_amdgcn_s_barrier();

  for (int t = 0; t < 32; t += 4) {
    compute(0);
    compute(4096);
    __builtin_amdgcn_s_barrier();  // release bufs 0,1 (all waves done reading)
    if (t + 4 < 32) {
      stage(0, (t + 4 + rot) & 31);
      stage(1, (t + 5 + rot) & 31);
      WAITV(4);                    // tiles t+2,t+3 landed; t+4,t+5 in flight
    } else {
      WAITV(0);                    // tail: drain tiles 30,31
    }
    __builtin_amdgcn_s_barrier();  // bufs 2,3 ready for everyone
    compute(8192);
    compute(12288);
    if (t + 4 < 32) {
      __builtin_amdgcn_s_barrier();  // release bufs 2,3
      stage(2, (t + 6 + rot) & 31);
      stage(3, (t + 7 + rot) & 31);
      WAITV(4);                      // tiles t+4,t+5 landed; t+6,t+7 in flight
      __builtin_amdgcn_s_barrier();  // bufs 0,1 ready
    }
  }

  // ---- epilogue: per-group combine of h-partners, bf16 store ----
  if (g == 0) {
    dred[w][0][c] = denacc[0][0];
    dred[w][1][c] = denacc[1][0];
  }
  __syncthreads();
  // 4 disjoint 8KB regions in retired staging LDS: (grp,qh)
  float* Rq = (grp ? (float*)&Vs[0][0] : (float*)&Ks[0][0]) + qh * 2048;
  if (h == 1) {
#pragma unroll
    for (int fd = 0; fd < 4; ++fd)
#pragma unroll
      for (int qg = 0; qg < 2; ++qg)
        *(f32x4*)&Rq[(qg * 16 + c) * 64 + fd * 16 + 4 * g] = attT[fd][qg];
  }
  __syncthreads();
  if (h == 0) {
    float inv[2];
#pragma unroll
    for (int qg = 0; qg < 2; ++qg)
      inv[qg] = 1.f / (dred[w][qg][c] + dred[w ^ 2][qg][c]);
#pragma unroll
    for (int fd = 0; fd < 4; ++fd)
#pragma unroll
      for (int qg = 0; qg < 2; ++qg) {
        f32x4 part = *(const f32x4*)&Rq[(qg * 16 + c) * 64 + fd * 16 + 4 * g];
        f32x4 tot = (attT[fd][qg] + part) * inv[qg];
        int q = q0 + qh * 32 + qg * 16 + c;
        *(uint2*)(attbufb + ((size_t)bh * S_LEN + q) * DKH + fd * 16 + 4 * g) =
            make_uint2(pk_bf16(tot[0], tot[1]), pk_bf16(tot[2], tot[3]));
      }
  }
}

// ---------------- head-reduce + a@Wo_eff + bias + residual + LayerNorm ----------------
__global__ __launch_bounds__(256) void fuse_out_ln_k(const u16* __restrict__ attbufb,
    const float* __restrict__ Woeff, const float* __restrict__ bo,
    const float* __restrict__ x, const float* __restrict__ gamma,
    const float* __restrict__ beta, float* __restrict__ out) {
  __shared__ float red[8][256];
  __shared__ __align__(16) float a[8][64];
  __shared__ float sred[8][4][2];
  int t = threadIdx.x;
  int r0 = blockIdx.x * 8;
  int d = t & 63, hg = t >> 6;
#pragma unroll
  for (int rr = 0; rr < 8; ++rr) {
    int m = r0 + rr, b = m >> 11, sr = m & 2047;
    float pa = 0.f;
#pragma unroll
    for (int hh = 0; hh < 4; ++hh) {
      int h = hg * 4 + hh;
      pa += bf2f(attbufb[(((size_t)(b * 16 + h)) * S_LEN + sr) * DKH + d]);
    }
    red[rr][t] = pa;
  }
  __syncthreads();
#pragma unroll
  for (int e = 0; e < 2; ++e) {
    int idx = t + e * 256;
    int rr = idx >> 6, dd = idx & 63;
    a[rr][dd] = red[rr][dd] + red[rr][64 + dd] + red[rr][128 + dd] + red[rr][192 + dd];
  }
  __syncthreads();

  float o[8][4];
#pragma unroll
  for (int rr = 0; rr < 8; ++rr) { o[rr][0] = o[rr][1] = o[rr][2] = o[rr][3] = 0.f; }
  int c4 = t * 4;
  for (int dd = 0; dd < 64; dd += 4) {
    float4 wv0 = *(const float4*)(Woeff + (size_t)(dd + 0) * DMODEL + c4);
    float4 wv1 = *(const float4*)(Woeff + (size_t)(dd + 1) * DMODEL + c4);
    float4 wv2 = *(const float4*)(Woeff + (size_t)(dd + 2) * DMODEL + c4);
    float4 wv3 = *(const float4*)(Woeff + (size_t)(dd + 3) * DMODEL + c4);
#pragma unroll
    for (int rr = 0; rr < 8; ++rr) {
      float4 av = *(const float4*)&a[rr][dd];
      o[rr][0] += av.x * wv0.x + av.y * wv1.x + av.z * wv2.x + av.w * wv3.x;
      o[rr][1] += av.x * wv0.y + av.y * wv1.y + av.z * wv2.y + av.w * wv3.y;
      o[rr][2] += av.x * wv0.z + av.y * wv1.z + av.z * wv2.z + av.w * wv3.z;
      o[rr][3] += av.x * wv0.w + av.y * wv1.w + av.z * wv2.w + av.w * wv3.w;
    }
  }
  float4 bv = *(const float4*)(bo + c4);
  int w = t >> 6, lane = t & 63;
#pragma unroll
  for (int rr = 0; rr < 8; ++rr) {
    int m = r0 + rr;
    float4 xv = *(const float4*)(x + (size_t)m * DMODEL + c4);
    o[rr][0] += bv.x + xv.x;
    o[rr][1] += bv.y + xv.y;
    o[rr][2] += bv.z + xv.z;
    o[rr][3] += bv.w + xv.w;
    float s = o[rr][0] + o[rr][1] + o[rr][2] + o[rr][3];
    float q = o[rr][0] * o[rr][0] + o[rr][1] * o[rr][1] + o[rr][2] * o[rr][2] + o[rr][3] * o[rr][3];
#pragma unroll
    for (int mm = 1; mm < 64; mm <<= 1) {
      s += __shfl_xor(s, mm, 64);
      q += __shfl_xor(q, mm, 64);
    }
    if (lane == 0) { sred[rr][w][0] = s; sred[rr][w][1] = q; }
  }
  __syncthreads();
  float4 gv = *(const float4*)(gamma + c4);
  float4 bev = *(const float4*)(beta + c4);
#pragma unroll
  for (int rr = 0; rr < 8; ++rr) {
    float s = sred[rr][0][0] + sred[rr][1][0] + sred[rr][2][0] + sred[rr][3][0];
    float q = sred[rr][0][1] + sred[rr][1][1] + sred[rr][2][1] + sred[rr][3][1];
    float mu = s * (1.f / 1024.f);
    float var = q * (1.f / 1024.f) - mu * mu;
    float rs = rsqrtf(var + 1e-6f);
    int m = r0 + rr;
    float4 ov;
    ov.x = gv.x * (o[rr][0] - mu) * rs + bev.x;
    ov.y = gv.y * (o[rr][1] - mu) * rs + bev.y;
    ov.z = gv.z * (o[rr][2] - mu) * rs + bev.z;
    ov.w = gv.w * (o[rr][3] - mu) * rs + bev.w;
    *(float4*)(out + (size_t)m * DMODEL + c4) = ov;
  }
}

extern "C" void kernel_launch(void* const* d_in, const int* in_sizes, int n_in,
                              void* d_out, int out_size, void* d_ws, size_t ws_size,
                              hipStream_t stream) {
  const float* x = (const float*)d_in[0];
  const float* Wq = (const float*)d_in[1];
  const float* Wk = (const float*)d_in[2];
  const float* Wv = (const float*)d_in[3];
  const float* Wo = (const float*)d_in[4];
  const float* bo = (const float*)d_in[5];
  const float* ps = (const float*)d_in[6];
  const float* ent = (const float*)d_in[7];
  const float* gamma = (const float*)d_in[8];
  const float* beta = (const float*)d_in[9];
  float* out = (float*)d_out;

  char* ws = (char*)d_ws;
  size_t o = 0;
  u16* xb = (u16*)(ws + o);    o += (size_t)MROWS * DMODEL * 2;        // 8 MB
  u16* Wb = (u16*)(ws + o);    o += (size_t)3072 * 1024 * 2;           // 6 MB
  u16* Qb = (u16*)(ws + o);    o += (size_t)BH_CNT * S_LEN * DKH * 2;  // 8 MB
  u16* Kb = (u16*)(ws + o);    o += (size_t)BH_CNT * S_LEN * DKH * 2;  // 8 MB
  u16* Vt = (u16*)(ws + o);    o += (size_t)BH_CNT * S_LEN * DKH * 2;  // 8 MB
  float* Woeff = (float*)(ws + o);   o += (size_t)DKH * DMODEL * 4;    // 256 KB
  u16* attbufb = (u16*)(ws + o);     o += (size_t)BH_CNT * S_LEN * DKH * 2;  // 8 MB

  prep_all_k<<<dim3(7424), dim3(256), 0, stream>>>(x, Wq, Wk, Wv, Wo, ps, ent,
                                                   xb, Wb, Woeff);
  gemm_qkv_k<<<dim3(192), dim3(512), 0, stream>>>(xb, Wb, Qb, Kb, Vt);
  attn_k<<<dim3(512), dim3(512), 0, stream>>>(Qb, Kb, Vt, attbufb);
  fuse_out_ln_k<<<dim3(512), dim3(256), 0, stream>>>(attbufb, Woeff, bo, x, gamma, beta, out);
}

// Round 17
// 124.191 us; speedup vs baseline: 1.0414x; 1.0231x over previous
//
#include <hip/hip_runtime.h>
#include <cstdint>
#include <cstddef>

#define S_LEN 2048
#define DMODEL 1024
#define NHEADS 16
#define DKH 64
#define MROWS 4096
#define BH_CNT 32

typedef __bf16 bf16x8 __attribute__((ext_vector_type(8)));
typedef __bf16 bf16x2 __attribute__((ext_vector_type(2)));
typedef float f32x4 __attribute__((ext_vector_type(4)));
typedef unsigned int u32x4 __attribute__((ext_vector_type(4)));
typedef unsigned int u32;
typedef unsigned short u16;

__device__ __forceinline__ u16 f2bfu(float f) {
  u32 u = __float_as_uint(f);
  return (u16)((u + 0x7FFFu + ((u >> 16) & 1u)) >> 16);
}

__device__ __forceinline__ float bf2f(u16 v) {
  return __uint_as_float((u32)v << 16);
}

// compiler-cast bf16 pack (lowers to v_cvt_pk_bf16_f32 on gfx950)
__device__ __forceinline__ u32 pk_bf16(float a, float b) {
  bf16x2 v;
  v[0] = (__bf16)a;
  v[1] = (__bf16)b;
  return __builtin_bit_cast(u32, v);
}

// true-swap cross-lane ops (gfx950): both operands modified
__device__ __forceinline__ void pl32swap(u32& a, u32& b) {
#if __has_builtin(__builtin_amdgcn_permlane32_swap)
  auto r = __builtin_amdgcn_permlane32_swap((int)a, (int)b, false, false);
  a = (u32)r[0]; b = (u32)r[1];
#else
  asm volatile("v_permlane32_swap_b32 %0, %1" : "+v"(a), "+v"(b));
#endif
}
__device__ __forceinline__ void pl16swap(u32& a, u32& b) {
#if __has_builtin(__builtin_amdgcn_permlane16_swap)
  auto r = __builtin_amdgcn_permlane16_swap((int)a, (int)b, false, false);
  a = (u32)r[0]; b = (u32)r[1];
#else
  asm volatile("v_permlane16_swap_b32 %0, %1" : "+v"(a), "+v"(b));
#endif
}

__device__ __forceinline__ void gload16(void* lds, const void* g) {
  __builtin_amdgcn_global_load_lds(
      (const __attribute__((address_space(1))) void*)g,
      (__attribute__((address_space(3))) void*)lds, 16, 0, 0);
}

// ---------------- merged prep: x->bf16 | W^T bf16 (K pre-scaled) | Wo_eff ----------------
// blocks [0,4096): x cast; [4096,7168): W transpose; [7168,7424): Wo_eff.
// K scale folds 1/sqrt(dk)*phase AND 1/(2pi): scores arrive in REVOLUTIONS.
__global__ __launch_bounds__(256) void prep_all_k(const float* __restrict__ x,
    const float* __restrict__ Wq, const float* __restrict__ Wk,
    const float* __restrict__ Wv, const float* __restrict__ Wo,
    const float* __restrict__ ps, const float* __restrict__ ent,
    u16* __restrict__ xb, u16* __restrict__ Wb, float* __restrict__ Woeff) {
  __shared__ float tile[32][33];
  int bid = blockIdx.x;
  int t = threadIdx.x;
  if (bid < 4096) {
    int i = (bid * 256 + t) * 4;
    float4 v = *(const float4*)(x + i);
    *(uint2*)(xb + i) = make_uint2(pk_bf16(v.x, v.y), pk_bf16(v.z, v.w));
  } else if (bid < 7168) {
    int lb = bid - 4096;
    int sel = lb >> 10, rem = lb & 1023;
    int k0 = (rem & 31) * 32, c0 = (rem >> 5) * 32;
    const float* W = sel == 0 ? Wq : (sel == 1 ? Wk : Wv);
    int tx = t & 31, ty = t >> 5;
#pragma unroll
    for (int i = 0; i < 4; ++i)
      tile[ty + i * 8][tx] = W[(size_t)(k0 + ty + i * 8) * DMODEL + c0 + tx];
    __syncthreads();
#pragma unroll
    for (int i = 0; i < 4; ++i) {
      int row = ty + i * 8;
      float v = tile[tx][row];
      if (sel == 1) v *= 0.019894367886486918f * ps[(c0 + row) >> 6];  // 0.125/(2pi)
      Wb[(size_t)(sel * 1024 + c0 + row) * DMODEL + k0 + tx] = f2bfu(v);
    }
  } else {
    __shared__ float e[16];
    if (t < 16) {
      float s = 0.f;
#pragma unroll
      for (int h = 0; h < 16; ++h) s += ent[h * 16 + t];
      e[t] = s;
    }
    __syncthreads();
    int gid = (bid - 7168) * 256 + t;
    int d = gid >> 10, j = gid & 1023;
    float acc = 0.f;
#pragma unroll
    for (int m = 0; m < 16; ++m) acc += e[m] * Wo[(size_t)((m << 6) + d) * DMODEL + j];
    Woeff[(size_t)d * DMODEL + j] = acc;
  }
}

// ---------------- QKV projection GEMM: [4096,1024] x [1024,3072] ----------------
// 256x256 tile, BK=32, 8 waves (2M x 4N), double-buffered staging (64KB LDS),
// one barrier per K-step. Grid 192 = 16x12, XCD-rectangle swizzle.
// Epilogue: two 128-row passes through retired 64KB LDS -> coalesced stores.
__global__ __launch_bounds__(512, 2) void gemm_qkv_k(const u16* __restrict__ xb,
    const u16* __restrict__ Wb, u16* __restrict__ Qb, u16* __restrict__ Kb,
    u16* __restrict__ Vt) {
  __shared__ __align__(16) u16 As[2][8192];  // [dbuf][256 x 32] = 32KB
  __shared__ __align__(16) u16 Bs[2][8192];  // [dbuf][256 x 32] = 32KB
  int bid = blockIdx.x;
  int xcd = bid & 7, wi = bid >> 3;           // 24 tiles per XCD
  int mt = (xcd >> 1) * 4 + (wi & 3);         // [0,16)
  int nt = (xcd & 1) * 6 + (wi >> 2);         // [0,12)
  int m0 = mt * 256, n0 = nt * 256;
  int tid = threadIdx.x;
  int lane = tid & 63, w = tid >> 6;
  int c = lane & 15, g = lane >> 4;
  int wr = w >> 2, wcn = w & 3;               // wave: M-half x N-quarter

  // staging source addresses (pre-swizzled chunks; (r+128)&3 == r&3)
  int r2 = tid >> 2, s2 = tid & 3;
  const u16* aS = xb + (size_t)(m0 + r2) * DMODEL + ((s2 ^ (r2 & 3)) * 8);
  const u16* bS = Wb + (size_t)(n0 + r2) * DMODEL + ((s2 ^ (r2 & 3)) * 8);

  // fragment read offsets (u16 units); row&3 == c&3 for all frags
  int xorc = (g ^ (c & 3)) * 8;
  int aoff[8], boff[4];
#pragma unroll
  for (int mf = 0; mf < 8; ++mf) aoff[mf] = (wr * 128 + mf * 16 + c) * 32 + xorc;
#pragma unroll
  for (int nf = 0; nf < 4; ++nf) boff[nf] = (wcn * 64 + nf * 16 + c) * 32 + xorc;

  f32x4 acc[8][4];
#pragma unroll
  for (int i = 0; i < 8; ++i)
#pragma unroll
    for (int j = 0; j < 4; ++j) acc[i][j] = (f32x4){0.f, 0.f, 0.f, 0.f};

  auto stage = [&](int buf, int kt) {
    gload16(&As[buf][tid * 8], aS + kt);
    gload16(&As[buf][4096 + tid * 8], aS + 128 * DMODEL + kt);
    gload16(&Bs[buf][tid * 8], bS + kt);
    gload16(&Bs[buf][4096 + tid * 8], bS + 128 * DMODEL + kt);
  };
  auto compute = [&](const int off) {  // off: 0 or 8192 (compile-time literal)
    bf16x8 bfr[4];
#pragma unroll
    for (int nf = 0; nf < 4; ++nf) bfr[nf] = *(const bf16x8*)(&Bs[0][0] + off + boff[nf]);
#pragma unroll
    for (int mf = 0; mf < 8; ++mf) {
      bf16x8 af = *(const bf16x8*)(&As[0][0] + off + aoff[mf]);
#pragma unroll
      for (int nf = 0; nf < 4; ++nf)
        acc[mf][nf] = __builtin_amdgcn_mfma_f32_16x16x32_bf16(af, bfr[nf], acc[mf][nf], 0, 0, 0);
    }
  };

  stage(0, 0);
  __syncthreads();
  for (int kt = 0; kt < DMODEL; kt += 64) {
    stage(1, kt + 32);
    compute(0);
    __syncthreads();
    if (kt + 64 < DMODEL) stage(0, kt + 64);
    compute(8192);
    __syncthreads();
  }

  // ---- epilogue: two 128-row passes through retired 64KB LDS ----
  int sel = nt >> 2;            // 0:Q 1:K 2:V
  int h0 = (nt & 3) * 4;        // first of 4 heads covered
  int b = m0 >> 11, sbase = m0 & 2047;
  char* Ls = (char*)&As[0][0];
#pragma unroll
  for (int half = 0; half < 2; ++half) {
    if (wr == half) {
      if (sel == 2) {
#pragma unroll
        for (int mf = 0; mf < 8; ++mf)
#pragma unroll
          for (int nf = 0; nf < 4; ++nf) {
            int n = wcn * 64 + nf * 16 + c;
            int mh = mf * 16 + 4 * g;
            *(uint2*)(Ls + n * 256 + ((mh * 2) ^ ((n & 7) << 4))) =
                make_uint2(pk_bf16(acc[mf][nf][0], acc[mf][nf][1]),
                           pk_bf16(acc[mf][nf][2], acc[mf][nf][3]));
          }
      } else {
#pragma unroll
        for (int mf = 0; mf < 8; ++mf)
#pragma unroll
          for (int nf = 0; nf < 4; ++nf) {
            int n = wcn * 64 + nf * 16 + c;
#pragma unroll
            for (int j = 0; j < 4; ++j) {
              int mh = mf * 16 + 4 * g + j;
              __bf16 hv = (__bf16)acc[mf][nf][j];
              *(u16*)(Ls + mh * 512 + ((n * 2) ^ ((mh & 7) << 4))) =
                  __builtin_bit_cast(u16, hv);
            }
          }
      }
    }
    __syncthreads();
    if (sel == 2) {
      int n = tid >> 1, cc = tid & 1;
      int head = h0 + (n >> 6), d = n & 63;
      u16* dst = Vt + ((size_t)(b * 16 + head) * DKH + d) * S_LEN + sbase + half * 128 + cc * 64;
#pragma unroll
      for (int kk = 0; kk < 8; ++kk)
        *(uint4*)(dst + kk * 8) =
            *(const uint4*)(Ls + n * 256 + ((cc * 128 + kk * 16) ^ ((n & 7) << 4)));
    } else {
      int r = tid >> 2, cc = tid & 3;
      int head = h0 + cc;
      u16* base = (sel == 0 ? Qb : Kb);
      u16* dst = base + ((size_t)(b * 16 + head) * S_LEN + sbase + half * 128 + r) * DKH;
#pragma unroll
      for (int kk = 0; kk < 8; ++kk)
        *(uint4*)(dst + kk * 8) =
            *(const uint4*)(Ls + r * 512 + ((cc * 128 + kk * 16) ^ ((r & 7) << 4)));
    }
    __syncthreads();
  }
}

// ---------------- fused cos-softmax flash attention (QK/SMPV pipelined) ----------------
// 8 waves / 512 threads (grp x h x qh), one shared staged K/V tile per block.
// QUAD-buffered staging, 2 tiles per barrier phase. T15-style reorder inside
// each phase: qk(A); qk(B); smpv(A); smpv(B) -- QK_B's MFMA issue hides
// sT_A's MFMA latency, and PV_A's MFMA cluster overlaps trans_B on the VALU.
// Compute recipe verified since round 7: S^T = mfma(K,Q); in-register softmax
// (v_cos + 2 fma + v_exp2, scores in revolutions); permlane32/16 swaps move
// P into the PV B-fragment; denominator via ones-row MFMA. bf16 output.
__global__ __launch_bounds__(512) void attn_k(const u16* __restrict__ Qb,
    const u16* __restrict__ Kb, const u16* __restrict__ Vt,
    u16* __restrict__ attbufb) {
  __shared__ __align__(16) u16 Ks[4][4096];  // [4buf][64x64] = 32KB
  __shared__ __align__(16) u16 Vs[4][4096];  // [4buf][64x64] = 32KB
  __shared__ float dred[8][2][16];
  int fid = blockIdx.x;
  int swz = (fid & 7) * 64 + (fid >> 3);  // 512 blocks, 8 XCDs -> bijective
  int bh = swz >> 4, qb = swz & 15;       // 4 heads per XCD (K/V 2MB L2-resident)
  int tid = threadIdx.x;
  int lane = tid & 63, w = tid >> 6;
  int c = lane & 15, g = lane >> 4;
  int grp = w >> 2, h = (w >> 1) & 1, qh = w & 1;
  int q0 = qb * 128 + grp * 64;
  const float L2E = 1.4426950408889634f;

  const u16* Kbase = Kb + (size_t)bh * S_LEN * DKH;
  const u16* Vbase = Vt + (size_t)bh * DKH * S_LEN;

  // staging: wave w stages chunk w (512 u16) of Ks and Vs (pre-swizzled src)
  int srow = w * 8 + (lane >> 3), slot = lane & 7, kp = slot ^ (srow & 7);
  const u16* kSrc = Kbase + (size_t)srow * DKH + kp * 8;
  const u16* vSrc = Vbase + (size_t)srow * S_LEN + kp * 8;
  auto stage = [&](int buf, int tile) {
    gload16(&Ks[buf][w * 512], kSrc + (size_t)tile * 64 * DKH);
    gload16(&Vs[buf][w * 512], vSrc + tile * 64);
  };

  int rot = qb * 2;  // rotated k-start spreads L2 sets across a head's blocks
  stage(0, rot & 31);
  stage(1, (rot + 1) & 31);

  bf16x8 qf[2][2];  // [qg][dk-half]
#pragma unroll
  for (int qg = 0; qg < 2; ++qg) {
    const u16* qp = Qb + ((size_t)bh * S_LEN + q0 + qh * 32 + qg * 16 + c) * DKH + g * 8;
    qf[qg][0] = *(const bf16x8*)qp;
    qf[qg][1] = *(const bf16x8*)(qp + 32);
  }
  bf16x8 onesf;
#pragma unroll
  for (int i = 0; i < 8; ++i) onesf[i] = (__bf16)1.0f;

  // precomputed LDS fragment pointers (buf0); bufN = +N*4096 u16 (compile-time)
  const u16* kptr[2][2];  // [fm][dk-half]
#pragma unroll
  for (int fm = 0; fm < 2; ++fm) {
    int row = h * 32 + fm * 16 + c;
    kptr[fm][0] = &Ks[0][row * 64 + ((g ^ (row & 7)) * 8)];
    kptr[fm][1] = &Ks[0][row * 64 + (((4 + g) ^ (row & 7)) * 8)];
  }
  const u16* vptr[4];  // [fd]
#pragma unroll
  for (int fd = 0; fd < 4; ++fd) {
    int vrow = fd * 16 + c;
    vptr[fd] = &Vs[0][vrow * 64 + (((4 * h + g) ^ (vrow & 7)) * 8)];
  }

  f32x4 attT[4][2];  // [fd][qg]
#pragma unroll
  for (int i = 0; i < 4; ++i)
#pragma unroll
    for (int qg = 0; qg < 2; ++qg) attT[i][qg] = (f32x4){0.f, 0.f, 0.f, 0.f};
  f32x4 denacc[2];
  denacc[0] = (f32x4){0.f, 0.f, 0.f, 0.f};
  denacc[1] = (f32x4){0.f, 0.f, 0.f, 0.f};

  auto qk = [&](const int off, f32x4 (&sT)[2][2]) {
    __builtin_amdgcn_s_setprio(1);
#pragma unroll
    for (int fm = 0; fm < 2; ++fm) {
      bf16x8 a0 = *(const bf16x8*)(kptr[fm][0] + off);
      bf16x8 a1 = *(const bf16x8*)(kptr[fm][1] + off);
#pragma unroll
      for (int qg = 0; qg < 2; ++qg) {
        f32x4 z = (f32x4){0.f, 0.f, 0.f, 0.f};
        z = __builtin_amdgcn_mfma_f32_16x16x32_bf16(a0, qf[qg][0], z, 0, 0, 0);
        sT[fm][qg] = __builtin_amdgcn_mfma_f32_16x16x32_bf16(a1, qf[qg][1], z, 0, 0, 0);
      }
    }
    __builtin_amdgcn_s_setprio(0);
  };
  auto smpv = [&](f32x4 (&sT)[2][2], const int off) {
    u32 wq[2][2][2];  // [qg][fm][r]
#pragma unroll
    for (int fm = 0; fm < 2; ++fm)
#pragma unroll
      for (int qg = 0; qg < 2; ++qg) {
        float pv[4];
#pragma unroll
        for (int j = 0; j < 4; ++j) {
          float cv = __builtin_amdgcn_cosf(sT[fm][qg][j]);  // revolutions
          float w2 = __fmaf_rn(cv, __fmaf_rn(0.2f * L2E, cv, L2E), -0.1f * L2E);
          pv[j] = __builtin_amdgcn_exp2f(w2);
        }
        wq[qg][fm][0] = pk_bf16(pv[0], pv[1]);
        wq[qg][fm][1] = pk_bf16(pv[2], pv[3]);
      }
    bf16x8 pf[2];
#pragma unroll
    for (int qg = 0; qg < 2; ++qg) {
      u32 b0 = wq[qg][0][0], b2 = wq[qg][1][0];
      pl32swap(b0, b2);
      pl16swap(b0, b2);
      u32 b1 = wq[qg][0][1], b3 = wq[qg][1][1];
      pl32swap(b1, b3);
      pl16swap(b1, b3);
      pf[qg] = __builtin_bit_cast(bf16x8, (u32x4){b0, b1, b2, b3});
    }
    __builtin_amdgcn_s_setprio(1);
#pragma unroll
    for (int fd = 0; fd < 4; ++fd) {
      bf16x8 vf = *(const bf16x8*)(vptr[fd] + off);
#pragma unroll
      for (int qg = 0; qg < 2; ++qg)
        attT[fd][qg] = __builtin_amdgcn_mfma_f32_16x16x32_bf16(vf, pf[qg], attT[fd][qg], 0, 0, 0);
    }
#pragma unroll
    for (int qg = 0; qg < 2; ++qg)
      denacc[qg] = __builtin_amdgcn_mfma_f32_16x16x32_bf16(onesf, pf[qg], denacc[qg], 0, 0, 0);
    __builtin_amdgcn_s_setprio(0);
  };

  f32x4 sA[2][2], sB[2][2];
  __syncthreads();
  for (int t = 0; t < 32; t += 4) {
    stage(2, (t + 2 + rot) & 31);
    stage(3, (t + 3 + rot) & 31);
    qk(0, sA);
    qk(4096, sB);
    smpv(sA, 0);
    smpv(sB, 4096);
    __syncthreads();
    if (t + 4 < 32) {
      stage(0, (t + 4 + rot) & 31);
      stage(1, (t + 5 + rot) & 31);
    }
    qk(8192, sA);
    qk(12288, sB);
    smpv(sA, 8192);
    smpv(sB, 12288);
    __syncthreads();
  }

  // ---- epilogue: per-group combine of h-partners, bf16 store ----
  if (g == 0) {
    dred[w][0][c] = denacc[0][0];
    dred[w][1][c] = denacc[1][0];
  }
  // 4 disjoint 8KB regions in retired staging LDS: (grp,qh)
  float* Rq = (grp ? (float*)&Vs[0][0] : (float*)&Ks[0][0]) + qh * 2048;
  if (h == 1) {
#pragma unroll
    for (int fd = 0; fd < 4; ++fd)
#pragma unroll
      for (int qg = 0; qg < 2; ++qg)
        *(f32x4*)&Rq[(qg * 16 + c) * 64 + fd * 16 + 4 * g] = attT[fd][qg];
  }
  __syncthreads();
  if (h == 0) {
    float inv[2];
#pragma unroll
    for (int qg = 0; qg < 2; ++qg)
      inv[qg] = 1.f / (dred[w][qg][c] + dred[w ^ 2][qg][c]);
#pragma unroll
    for (int fd = 0; fd < 4; ++fd)
#pragma unroll
      for (int qg = 0; qg < 2; ++qg) {
        f32x4 part = *(const f32x4*)&Rq[(qg * 16 + c) * 64 + fd * 16 + 4 * g];
        f32x4 tot = (attT[fd][qg] + part) * inv[qg];
        int q = q0 + qh * 32 + qg * 16 + c;
        *(uint2*)(attbufb + ((size_t)bh * S_LEN + q) * DKH + fd * 16 + 4 * g) =
            make_uint2(pk_bf16(tot[0], tot[1]), pk_bf16(tot[2], tot[3]));
      }
  }
}

// ---------------- head-reduce + a@Wo_eff + bias + residual + LayerNorm ----------------
__global__ __launch_bounds__(256) void fuse_out_ln_k(const u16* __restrict__ attbufb,
    const float* __restrict__ Woeff, const float* __restrict__ bo,
    const float* __restrict__ x, const float* __restrict__ gamma,
    const float* __restrict__ beta, float* __restrict__ out) {
  __shared__ float red[8][256];
  __shared__ __align__(16) float a[8][64];
  __shared__ float sred[8][4][2];
  int t = threadIdx.x;
  int r0 = blockIdx.x * 8;
  int d = t & 63, hg = t >> 6;
#pragma unroll
  for (int rr = 0; rr < 8; ++rr) {
    int m = r0 + rr, b = m >> 11, sr = m & 2047;
    float pa = 0.f;
#pragma unroll
    for (int hh = 0; hh < 4; ++hh) {
      int h = hg * 4 + hh;
      pa += bf2f(attbufb[(((size_t)(b * 16 + h)) * S_LEN + sr) * DKH + d]);
    }
    red[rr][t] = pa;
  }
  __syncthreads();
#pragma unroll
  for (int e = 0; e < 2; ++e) {
    int idx = t + e * 256;
    int rr = idx >> 6, dd = idx & 63;
    a[rr][dd] = red[rr][dd] + red[rr][64 + dd] + red[rr][128 + dd] + red[rr][192 + dd];
  }
  __syncthreads();

  float o[8][4];
#pragma unroll
  for (int rr = 0; rr < 8; ++rr) { o[rr][0] = o[rr][1] = o[rr][2] = o[rr][3] = 0.f; }
  int c4 = t * 4;
  for (int dd = 0; dd < 64; dd += 4) {
    float4 wv0 = *(const float4*)(Woeff + (size_t)(dd + 0) * DMODEL + c4);
    float4 wv1 = *(const float4*)(Woeff + (size_t)(dd + 1) * DMODEL + c4);
    float4 wv2 = *(const float4*)(Woeff + (size_t)(dd + 2) * DMODEL + c4);
    float4 wv3 = *(const float4*)(Woeff + (size_t)(dd + 3) * DMODEL + c4);
#pragma unroll
    for (int rr = 0; rr < 8; ++rr) {
      float4 av = *(const float4*)&a[rr][dd];
      o[rr][0] += av.x * wv0.x + av.y * wv1.x + av.z * wv2.x + av.w * wv3.x;
      o[rr][1] += av.x * wv0.y + av.y * wv1.y + av.z * wv2.y + av.w * wv3.y;
      o[rr][2] += av.x * wv0.z + av.y * wv1.z + av.z * wv2.z + av.w * wv3.z;
      o[rr][3] += av.x * wv0.w + av.y * wv1.w + av.z * wv2.w + av.w * wv3.w;
    }
  }
  float4 bv = *(const float4*)(bo + c4);
  int w = t >> 6, lane = t & 63;
#pragma unroll
  for (int rr = 0; rr < 8; ++rr) {
    int m = r0 + rr;
    float4 xv = *(const float4*)(x + (size_t)m * DMODEL + c4);
    o[rr][0] += bv.x + xv.x;
    o[rr][1] += bv.y + xv.y;
    o[rr][2] += bv.z + xv.z;
    o[rr][3] += bv.w + xv.w;
    float s = o[rr][0] + o[rr][1] + o[rr][2] + o[rr][3];
    float q = o[rr][0] * o[rr][0] + o[rr][1] * o[rr][1] + o[rr][2] * o[rr][2] + o[rr][3] * o[rr][3];
#pragma unroll
    for (int mm = 1; mm < 64; mm <<= 1) {
      s += __shfl_xor(s, mm, 64);
      q += __shfl_xor(q, mm, 64);
    }
    if (lane == 0) { sred[rr][w][0] = s; sred[rr][w][1] = q; }
  }
  __syncthreads();
  float4 gv = *(const float4*)(gamma + c4);
  float4 bev = *(const float4*)(beta + c4);
#pragma unroll
  for (int rr = 0; rr < 8; ++rr) {
    float s = sred[rr][0][0] + sred[rr][1][0] + sred[rr][2][0] + sred[rr][3][0];
    float q = sred[rr][0][1] + sred[rr][1][1] + sred[rr][2][1] + sred[rr][3][1];
    float mu = s * (1.f / 1024.f);
    float var = q * (1.f / 1024.f) - mu * mu;
    float rs = rsqrtf(var + 1e-6f);
    int m = r0 + rr;
    float4 ov;
    ov.x = gv.x * (o[rr][0] - mu) * rs + bev.x;
    ov.y = gv.y * (o[rr][1] - mu) * rs + bev.y;
    ov.z = gv.z * (o[rr][2] - mu) * rs + bev.z;
    ov.w = gv.w * (o[rr][3] - mu) * rs + bev.w;
    *(float4*)(out + (size_t)m * DMODEL + c4) = ov;
  }
}

extern "C" void kernel_launch(void* const* d_in, const int* in_sizes, int n_in,
                              void* d_out, int out_size, void* d_ws, size_t ws_size,
                              hipStream_t stream) {
  const float* x = (const float*)d_in[0];
  const float* Wq = (const float*)d_in[1];
  const float* Wk = (const float*)d_in[2];
  const float* Wv = (const float*)d_in[3];
  const float* Wo = (const float*)d_in[4];
  const float* bo = (const float*)d_in[5];
  const float* ps = (const float*)d_in[6];
  const float* ent = (const float*)d_in[7];
  const float* gamma = (const float*)d_in[8];
  const float* beta = (const float*)d_in[9];
  float* out = (float*)d_out;

  char* ws = (char*)d_ws;
  size_t o = 0;
  u16* xb = (u16*)(ws + o);    o += (size_t)MROWS * DMODEL * 2;        // 8 MB
  u16* Wb = (u16*)(ws + o);    o += (size_t)3072 * 1024 * 2;           // 6 MB
  u16* Qb = (u16*)(ws + o);    o += (size_t)BH_CNT * S_LEN * DKH * 2;  // 8 MB
  u16* Kb = (u16*)(ws + o);    o += (size_t)BH_CNT * S_LEN * DKH * 2;  // 8 MB
  u16* Vt = (u16*)(ws + o);    o += (size_t)BH_CNT * S_LEN * DKH * 2;  // 8 MB
  float* Woeff = (float*)(ws + o);   o += (size_t)DKH * DMODEL * 4;    // 256 KB
  u16* attbufb = (u16*)(ws + o);     o += (size_t)BH_CNT * S_LEN * DKH * 2;  // 8 MB

  prep_all_k<<<dim3(7424), dim3(256), 0, stream>>>(x, Wq, Wk, Wv, Wo, ps, ent,
                                                   xb, Wb, Woeff);
  gemm_qkv_k<<<dim3(192), dim3(512), 0, stream>>>(xb, Wb, Qb, Kb, Vt);
  attn_k<<<dim3(512), dim3(512), 0, stream>>>(Qb, Kb, Vt, attbufb);
  fuse_out_ln_k<<<dim3(512), dim3(256), 0, stream>>>(attbufb, Woeff, bo, x, gamma, beta, out);
}

// Round 18
// 121.143 us; speedup vs baseline: 1.0676x; 1.0252x over previous
//
#include <hip/hip_runtime.h>
#include <cstdint>
#include <cstddef>

#define S_LEN 2048
#define DMODEL 1024
#define NHEADS 16
#define DKH 64
#define MROWS 4096
#define BH_CNT 32

typedef __bf16 bf16x8 __attribute__((ext_vector_type(8)));
typedef __bf16 bf16x2 __attribute__((ext_vector_type(2)));
typedef float f32x4 __attribute__((ext_vector_type(4)));
typedef unsigned int u32x4 __attribute__((ext_vector_type(4)));
typedef unsigned int u32;
typedef unsigned short u16;

__device__ __forceinline__ u16 f2bfu(float f) {
  u32 u = __float_as_uint(f);
  return (u16)((u + 0x7FFFu + ((u >> 16) & 1u)) >> 16);
}

__device__ __forceinline__ float bf2f(u16 v) {
  return __uint_as_float((u32)v << 16);
}

// compiler-cast bf16 pack (lowers to v_cvt_pk_bf16_f32 on gfx950)
__device__ __forceinline__ u32 pk_bf16(float a, float b) {
  bf16x2 v;
  v[0] = (__bf16)a;
  v[1] = (__bf16)b;
  return __builtin_bit_cast(u32, v);
}

// true-swap cross-lane ops (gfx950): both operands modified
__device__ __forceinline__ void pl32swap(u32& a, u32& b) {
#if __has_builtin(__builtin_amdgcn_permlane32_swap)
  auto r = __builtin_amdgcn_permlane32_swap((int)a, (int)b, false, false);
  a = (u32)r[0]; b = (u32)r[1];
#else
  asm volatile("v_permlane32_swap_b32 %0, %1" : "+v"(a), "+v"(b));
#endif
}
__device__ __forceinline__ void pl16swap(u32& a, u32& b) {
#if __has_builtin(__builtin_amdgcn_permlane16_swap)
  auto r = __builtin_amdgcn_permlane16_swap((int)a, (int)b, false, false);
  a = (u32)r[0]; b = (u32)r[1];
#else
  asm volatile("v_permlane16_swap_b32 %0, %1" : "+v"(a), "+v"(b));
#endif
}

__device__ __forceinline__ void gload16(void* lds, const void* g) {
  __builtin_amdgcn_global_load_lds(
      (const __attribute__((address_space(1))) void*)g,
      (__attribute__((address_space(3))) void*)lds, 16, 0, 0);
}

// wave-local counted wait on outstanding global loads (rule #18: fence after)
#define WAITV(n)                                            \
  do {                                                      \
    asm volatile("s_waitcnt vmcnt(" #n ")" ::: "memory");   \
    __builtin_amdgcn_sched_barrier(0);                      \
  } while (0)

// raw barrier: compiler memory fence, NO hardware waitcnt drain
#define SBAR() asm volatile("s_barrier" ::: "memory")

// ---------------- merged prep: x->bf16 | W^T bf16 (K pre-scaled) | Wo_eff ----------------
// blocks [0,4096): x cast; [4096,7168): W transpose; [7168,7424): Wo_eff.
// K scale folds 1/sqrt(dk)*phase AND 1/(2pi): scores arrive in REVOLUTIONS.
__global__ __launch_bounds__(256) void prep_all_k(const float* __restrict__ x,
    const float* __restrict__ Wq, const float* __restrict__ Wk,
    const float* __restrict__ Wv, const float* __restrict__ Wo,
    const float* __restrict__ ps, const float* __restrict__ ent,
    u16* __restrict__ xb, u16* __restrict__ Wb, float* __restrict__ Woeff) {
  __shared__ float tile[32][33];
  int bid = blockIdx.x;
  int t = threadIdx.x;
  if (bid < 4096) {
    int i = (bid * 256 + t) * 4;
    float4 v = *(const float4*)(x + i);
    *(uint2*)(xb + i) = make_uint2(pk_bf16(v.x, v.y), pk_bf16(v.z, v.w));
  } else if (bid < 7168) {
    int lb = bid - 4096;
    int sel = lb >> 10, rem = lb & 1023;
    int k0 = (rem & 31) * 32, c0 = (rem >> 5) * 32;
    const float* W = sel == 0 ? Wq : (sel == 1 ? Wk : Wv);
    int tx = t & 31, ty = t >> 5;
#pragma unroll
    for (int i = 0; i < 4; ++i)
      tile[ty + i * 8][tx] = W[(size_t)(k0 + ty + i * 8) * DMODEL + c0 + tx];
    __syncthreads();
#pragma unroll
    for (int i = 0; i < 4; ++i) {
      int row = ty + i * 8;
      float v = tile[tx][row];
      if (sel == 1) v *= 0.019894367886486918f * ps[(c0 + row) >> 6];  // 0.125/(2pi)
      Wb[(size_t)(sel * 1024 + c0 + row) * DMODEL + k0 + tx] = f2bfu(v);
    }
  } else {
    __shared__ float e[16];
    if (t < 16) {
      float s = 0.f;
#pragma unroll
      for (int h = 0; h < 16; ++h) s += ent[h * 16 + t];
      e[t] = s;
    }
    __syncthreads();
    int gid = (bid - 7168) * 256 + t;
    int d = gid >> 10, j = gid & 1023;
    float acc = 0.f;
#pragma unroll
    for (int m = 0; m < 16; ++m) acc += e[m] * Wo[(size_t)((m << 6) + d) * DMODEL + j];
    Woeff[(size_t)d * DMODEL + j] = acc;
  }
}

// ---------------- QKV projection GEMM (8-phase schedule, T2+T3+T4+T5) ----------------
// 256x256 tile, BK=64, 8 waves (2M x 4N), 128KB LDS (2 K-tile bufs, each
// A[2 halves 16KB] + B[2 halves 16KB]). Per K-tile 4 phases: {ds-read one
// C-quadrant's frags || stage 1 half-tile -> s_barrier -> setprio 16 MFMA
// -> s_barrier}; counted vmcnt(4) only at phases 4/8 (2 half-tiles stay in
// flight across barriers). Stage map derived safe: P1,P2: tile(2j+1).B;
// P3..P6: tile(2j+2).A0,A1,B0,B1; P7,P8: tile(2j+3).A. Grid 192, XCD swizzle.
__global__ __launch_bounds__(512, 1) void gemm_qkv_k(const u16* __restrict__ xb,
    const u16* __restrict__ Wb, u16* __restrict__ Qb, u16* __restrict__ Kb,
    u16* __restrict__ Vt) {
  __shared__ __align__(16) u16 SM[65536];  // 128KB
  int bid = blockIdx.x;
  int xcd = bid & 7, wi = bid >> 3;           // 24 tiles per XCD
  int mt = (xcd >> 1) * 4 + (wi & 3);         // [0,16)
  int nt = (xcd & 1) * 6 + (wi >> 2);         // [0,12)
  int m0 = mt * 256, n0 = nt * 256;
  int tid = threadIdx.x;
  int lane = tid & 63, w = tid >> 6;
  int c = lane & 15, g = lane >> 4;
  int wr = w >> 2, wcn = w & 3;               // wave: M-half x N-quarter

  // staging sources (pre-swizzled chunk; row&7 == (tid>>3)&7)
  int srow8 = tid >> 3;
  int sch = (tid & 7) ^ (srow8 & 7);
  const u16* aS = xb + (size_t)(m0 + srow8) * DMODEL + sch * 8;
  const u16* bS = Wb + (size_t)(n0 + srow8) * DMODEL + sch * 8;

  // fragment read bases (u16 units); chunk offsets per kk
  int cho[2];
  cho[0] = (g ^ (c & 7)) * 8;
  cho[1] = ((4 + g) ^ (c & 7)) * 8;
  const u16* aRow = SM + wr * 8192 + c * 64;                          // + d + mf*1024 + cho[kk]
  const u16* bRow = SM + 16384 + (wcn >> 1) * 8192 + ((wcn & 1) * 64 + c) * 64;  // + d + nf*1024 + cho[kk]

  // stage lambdas: one half-tile = 2 gload16
  auto stA = [&](int d, int h, int kt) {
    gload16(SM + d + h * 8192 + tid * 8, aS + (size_t)(h * 128) * DMODEL + kt);
    gload16(SM + d + h * 8192 + 4096 + tid * 8, aS + (size_t)(h * 128 + 64) * DMODEL + kt);
  };
  auto stB = [&](int d, int h, int kt) {
    gload16(SM + d + 16384 + h * 8192 + tid * 8, bS + (size_t)(h * 128) * DMODEL + kt);
    gload16(SM + d + 16384 + h * 8192 + 4096 + tid * 8, bS + (size_t)(h * 128 + 64) * DMODEL + kt);
  };

  f32x4 acc[8][4];
#pragma unroll
  for (int i = 0; i < 8; ++i)
#pragma unroll
    for (int j = 0; j < 4; ++j) acc[i][j] = (f32x4){0.f, 0.f, 0.f, 0.f};

  bf16x8 a03[4][2], a47[4][2], b01[2][2], b23[2][2];

  auto rdA03 = [&](const int d) {
#pragma unroll
    for (int mf = 0; mf < 4; ++mf)
#pragma unroll
      for (int kk = 0; kk < 2; ++kk)
        a03[mf][kk] = *(const bf16x8*)(aRow + d + mf * 1024 + cho[kk]);
  };
  auto rdA47 = [&](const int d) {
#pragma unroll
    for (int mf = 0; mf < 4; ++mf)
#pragma unroll
      for (int kk = 0; kk < 2; ++kk)
        a47[mf][kk] = *(const bf16x8*)(aRow + d + (4 + mf) * 1024 + cho[kk]);
  };
  auto rdB01 = [&](const int d) {
#pragma unroll
    for (int nf = 0; nf < 2; ++nf)
#pragma unroll
      for (int kk = 0; kk < 2; ++kk)
        b01[nf][kk] = *(const bf16x8*)(bRow + d + nf * 1024 + cho[kk]);
  };
  auto rdB23 = [&](const int d) {
#pragma unroll
    for (int nf = 0; nf < 2; ++nf)
#pragma unroll
      for (int kk = 0; kk < 2; ++kk)
        b23[nf][kk] = *(const bf16x8*)(bRow + d + (2 + nf) * 1024 + cho[kk]);
  };
  auto mm = [&](bf16x8 (&aa)[4][2], bf16x8 (&bb)[2][2], const int mb, const int nb) {
    __builtin_amdgcn_s_setprio(1);
#pragma unroll
    for (int mf = 0; mf < 4; ++mf)
#pragma unroll
      for (int nf = 0; nf < 2; ++nf)
#pragma unroll
        for (int kk = 0; kk < 2; ++kk)
          acc[mb + mf][nb + nf] =
              __builtin_amdgcn_mfma_f32_16x16x32_bf16(aa[mf][kk], bb[nf][kk], acc[mb + mf][nb + nf], 0, 0, 0);
    __builtin_amdgcn_s_setprio(0);
  };

  // prologue: tile0 (all 4 halves) + tile1.A -> drain, barrier
  stA(0, 0, 0); stA(0, 1, 0); stB(0, 0, 0); stB(0, 1, 0);
  stA(32768, 0, 64); stA(32768, 1, 64);
  __syncthreads();

  for (int j = 0; j < 8; ++j) {
    const bool more = (j < 7);
    int kt1 = (2 * j + 1) * 64, kt2 = (2 * j + 2) * 64, kt3 = (2 * j + 3) * 64;
    // ---- K-tile 2j (buf0) ----
    rdA03(0); rdB01(0);            // P1
    stB(32768, 0, kt1);
    SBAR();
    mm(a03, b01, 0, 0);
    SBAR();
    rdA47(0);                      // P2
    stB(32768, 1, kt1);
    SBAR();
    mm(a47, b01, 4, 0);
    SBAR();
    rdB23(0);                      // P3
    if (more) stA(0, 0, kt2);
    SBAR();
    mm(a03, b23, 0, 2);
    SBAR();
    if (more) {                    // P4
      stA(0, 1, kt2);
      WAITV(4);
    } else {
      WAITV(0);
    }
    SBAR();
    mm(a47, b23, 4, 2);
    SBAR();
    // ---- K-tile 2j+1 (buf1) ----
    rdA03(32768); rdB01(32768);    // P5
    if (more) stB(0, 0, kt2);
    SBAR();
    mm(a03, b01, 0, 0);
    SBAR();
    rdA47(32768);                  // P6
    if (more) stB(0, 1, kt2);
    SBAR();
    mm(a47, b01, 4, 0);
    SBAR();
    rdB23(32768);                  // P7
    if (more) stA(32768, 0, kt3);
    SBAR();
    mm(a03, b23, 0, 2);
    SBAR();
    if (more) {                    // P8
      stA(32768, 1, kt3);
      WAITV(4);
    }
    SBAR();
    mm(a47, b23, 4, 2);
    SBAR();
  }

  // ---- epilogue: two 128-row passes through retired LDS (64KB used) ----
  __syncthreads();
  int sel = nt >> 2;            // 0:Q 1:K 2:V
  int h0 = (nt & 3) * 4;        // first of 4 heads covered
  int b = m0 >> 11, sbase = m0 & 2047;
  char* Ls = (char*)&SM[0];
#pragma unroll
  for (int half = 0; half < 2; ++half) {
    if (wr == half) {
      if (sel == 2) {
#pragma unroll
        for (int mf = 0; mf < 8; ++mf)
#pragma unroll
          for (int nf = 0; nf < 4; ++nf) {
            int n = wcn * 64 + nf * 16 + c;
            int mh = mf * 16 + 4 * g;
            *(uint2*)(Ls + n * 256 + ((mh * 2) ^ ((n & 7) << 4))) =
                make_uint2(pk_bf16(acc[mf][nf][0], acc[mf][nf][1]),
                           pk_bf16(acc[mf][nf][2], acc[mf][nf][3]));
          }
      } else {
#pragma unroll
        for (int mf = 0; mf < 8; ++mf)
#pragma unroll
          for (int nf = 0; nf < 4; ++nf) {
            int n = wcn * 64 + nf * 16 + c;
#pragma unroll
            for (int jj = 0; jj < 4; ++jj) {
              int mh = mf * 16 + 4 * g + jj;
              __bf16 hv = (__bf16)acc[mf][nf][jj];
              *(u16*)(Ls + mh * 512 + ((n * 2) ^ ((mh & 7) << 4))) =
                  __builtin_bit_cast(u16, hv);
            }
          }
      }
    }
    __syncthreads();
    if (sel == 2) {
      int n = tid >> 1, cc = tid & 1;
      int head = h0 + (n >> 6), d = n & 63;
      u16* dst = Vt + ((size_t)(b * 16 + head) * DKH + d) * S_LEN + sbase + half * 128 + cc * 64;
#pragma unroll
      for (int kk = 0; kk < 8; ++kk)
        *(uint4*)(dst + kk * 8) =
            *(const uint4*)(Ls + n * 256 + ((cc * 128 + kk * 16) ^ ((n & 7) << 4)));
    } else {
      int r = tid >> 2, cc = tid & 3;
      int head = h0 + cc;
      u16* base = (sel == 0 ? Qb : Kb);
      u16* dst = base + ((size_t)(b * 16 + head) * S_LEN + sbase + half * 128 + r) * DKH;
#pragma unroll
      for (int kk = 0; kk < 8; ++kk)
        *(uint4*)(dst + kk * 8) =
            *(const uint4*)(Ls + r * 512 + ((cc * 128 + kk * 16) ^ ((r & 7) << 4)));
    }
    __syncthreads();
  }
}

// ---------------- fused cos-softmax flash attention (QK/SMPV pipelined) ----------------
// 8 waves / 512 threads (grp x h x qh), one shared staged K/V tile per block.
// QUAD-buffered staging, 2 tiles per barrier phase; qk/smpv split so QK_B's
// MFMA issue hides sT_A latency and PV_A overlaps trans_B. Verified recipe:
// S^T = mfma(K,Q); in-register softmax (v_cos + 2 fma + v_exp2, revolutions);
// permlane32/16 swaps move P into the PV B-fragment; denominator via
// ones-row MFMA. bf16 output.
__global__ __launch_bounds__(512) void attn_k(const u16* __restrict__ Qb,
    const u16* __restrict__ Kb, const u16* __restrict__ Vt,
    u16* __restrict__ attbufb) {
  __shared__ __align__(16) u16 Ks[4][4096];  // [4buf][64x64] = 32KB
  __shared__ __align__(16) u16 Vs[4][4096];  // [4buf][64x64] = 32KB
  __shared__ float dred[8][2][16];
  int fid = blockIdx.x;
  int swz = (fid & 7) * 64 + (fid >> 3);  // 512 blocks, 8 XCDs -> bijective
  int bh = swz >> 4, qb = swz & 15;       // 4 heads per XCD (K/V 2MB L2-resident)
  int tid = threadIdx.x;
  int lane = tid & 63, w = tid >> 6;
  int c = lane & 15, g = lane >> 4;
  int grp = w >> 2, h = (w >> 1) & 1, qh = w & 1;
  int q0 = qb * 128 + grp * 64;
  const float L2E = 1.4426950408889634f;

  const u16* Kbase = Kb + (size_t)bh * S_LEN * DKH;
  const u16* Vbase = Vt + (size_t)bh * DKH * S_LEN;

  // staging: wave w stages chunk w (512 u16) of Ks and Vs (pre-swizzled src)
  int srow = w * 8 + (lane >> 3), slot = lane & 7, kp = slot ^ (srow & 7);
  const u16* kSrc = Kbase + (size_t)srow * DKH + kp * 8;
  const u16* vSrc = Vbase + (size_t)srow * S_LEN + kp * 8;
  auto stage = [&](int buf, int tile) {
    gload16(&Ks[buf][w * 512], kSrc + (size_t)tile * 64 * DKH);
    gload16(&Vs[buf][w * 512], vSrc + tile * 64);
  };

  int rot = qb * 2;  // rotated k-start spreads L2 sets across a head's blocks
  stage(0, rot & 31);
  stage(1, (rot + 1) & 31);

  bf16x8 qf[2][2];  // [qg][dk-half]
#pragma unroll
  for (int qg = 0; qg < 2; ++qg) {
    const u16* qp = Qb + ((size_t)bh * S_LEN + q0 + qh * 32 + qg * 16 + c) * DKH + g * 8;
    qf[qg][0] = *(const bf16x8*)qp;
    qf[qg][1] = *(const bf16x8*)(qp + 32);
  }
  bf16x8 onesf;
#pragma unroll
  for (int i = 0; i < 8; ++i) onesf[i] = (__bf16)1.0f;

  // precomputed LDS fragment pointers (buf0); bufN = +N*4096 u16 (compile-time)
  const u16* kptr[2][2];  // [fm][dk-half]
#pragma unroll
  for (int fm = 0; fm < 2; ++fm) {
    int row = h * 32 + fm * 16 + c;
    kptr[fm][0] = &Ks[0][row * 64 + ((g ^ (row & 7)) * 8)];
    kptr[fm][1] = &Ks[0][row * 64 + (((4 + g) ^ (row & 7)) * 8)];
  }
  const u16* vptr[4];  // [fd]
#pragma unroll
  for (int fd = 0; fd < 4; ++fd) {
    int vrow = fd * 16 + c;
    vptr[fd] = &Vs[0][vrow * 64 + (((4 * h + g) ^ (vrow & 7)) * 8)];
  }

  f32x4 attT[4][2];  // [fd][qg]
#pragma unroll
  for (int i = 0; i < 4; ++i)
#pragma unroll
    for (int qg = 0; qg < 2; ++qg) attT[i][qg] = (f32x4){0.f, 0.f, 0.f, 0.f};
  f32x4 denacc[2];
  denacc[0] = (f32x4){0.f, 0.f, 0.f, 0.f};
  denacc[1] = (f32x4){0.f, 0.f, 0.f, 0.f};

  auto qk = [&](const int off, f32x4 (&sT)[2][2]) {
    __builtin_amdgcn_s_setprio(1);
#pragma unroll
    for (int fm = 0; fm < 2; ++fm) {
      bf16x8 a0 = *(const bf16x8*)(kptr[fm][0] + off);
      bf16x8 a1 = *(const bf16x8*)(kptr[fm][1] + off);
#pragma unroll
      for (int qg = 0; qg < 2; ++qg) {
        f32x4 z = (f32x4){0.f, 0.f, 0.f, 0.f};
        z = __builtin_amdgcn_mfma_f32_16x16x32_bf16(a0, qf[qg][0], z, 0, 0, 0);
        sT[fm][qg] = __builtin_amdgcn_mfma_f32_16x16x32_bf16(a1, qf[qg][1], z, 0, 0, 0);
      }
    }
    __builtin_amdgcn_s_setprio(0);
  };
  auto smpv = [&](f32x4 (&sT)[2][2], const int off) {
    u32 wq[2][2][2];  // [qg][fm][r]
#pragma unroll
    for (int fm = 0; fm < 2; ++fm)
#pragma unroll
      for (int qg = 0; qg < 2; ++qg) {
        float pv[4];
#pragma unroll
        for (int j = 0; j < 4; ++j) {
          float cv = __builtin_amdgcn_cosf(sT[fm][qg][j]);  // revolutions
          float w2 = __fmaf_rn(cv, __fmaf_rn(0.2f * L2E, cv, L2E), -0.1f * L2E);
          pv[j] = __builtin_amdgcn_exp2f(w2);
        }
        wq[qg][fm][0] = pk_bf16(pv[0], pv[1]);
        wq[qg][fm][1] = pk_bf16(pv[2], pv[3]);
      }
    bf16x8 pf[2];
#pragma unroll
    for (int qg = 0; qg < 2; ++qg) {
      u32 b0 = wq[qg][0][0], b2 = wq[qg][1][0];
      pl32swap(b0, b2);
      pl16swap(b0, b2);
      u32 b1 = wq[qg][0][1], b3 = wq[qg][1][1];
      pl32swap(b1, b3);
      pl16swap(b1, b3);
      pf[qg] = __builtin_bit_cast(bf16x8, (u32x4){b0, b1, b2, b3});
    }
    __builtin_amdgcn_s_setprio(1);
#pragma unroll
    for (int fd = 0; fd < 4; ++fd) {
      bf16x8 vf = *(const bf16x8*)(vptr[fd] + off);
#pragma unroll
      for (int qg = 0; qg < 2; ++qg)
        attT[fd][qg] = __builtin_amdgcn_mfma_f32_16x16x32_bf16(vf, pf[qg], attT[fd][qg], 0, 0, 0);
    }
#pragma unroll
    for (int qg = 0; qg < 2; ++qg)
      denacc[qg] = __builtin_amdgcn_mfma_f32_16x16x32_bf16(onesf, pf[qg], denacc[qg], 0, 0, 0);
    __builtin_amdgcn_s_setprio(0);
  };

  f32x4 sA[2][2], sB[2][2];
  __syncthreads();
  for (int t = 0; t < 32; t += 4) {
    stage(2, (t + 2 + rot) & 31);
    stage(3, (t + 3 + rot) & 31);
    qk(0, sA);
    qk(4096, sB);
    smpv(sA, 0);
    smpv(sB, 4096);
    __syncthreads();
    if (t + 4 < 32) {
      stage(0, (t + 4 + rot) & 31);
      stage(1, (t + 5 + rot) & 31);
    }
    qk(8192, sA);
    qk(12288, sB);
    smpv(sA, 8192);
    smpv(sB, 12288);
    __syncthreads();
  }

  // ---- epilogue: per-group combine of h-partners, bf16 store ----
  if (g == 0) {
    dred[w][0][c] = denacc[0][0];
    dred[w][1][c] = denacc[1][0];
  }
  // 4 disjoint 8KB regions in retired staging LDS: (grp,qh)
  float* Rq = (grp ? (float*)&Vs[0][0] : (float*)&Ks[0][0]) + qh * 2048;
  if (h == 1) {
#pragma unroll
    for (int fd = 0; fd < 4; ++fd)
#pragma unroll
      for (int qg = 0; qg < 2; ++qg)
        *(f32x4*)&Rq[(qg * 16 + c) * 64 + fd * 16 + 4 * g] = attT[fd][qg];
  }
  __syncthreads();
  if (h == 0) {
    float inv[2];
#pragma unroll
    for (int qg = 0; qg < 2; ++qg)
      inv[qg] = 1.f / (dred[w][qg][c] + dred[w ^ 2][qg][c]);
#pragma unroll
    for (int fd = 0; fd < 4; ++fd)
#pragma unroll
      for (int qg = 0; qg < 2; ++qg) {
        f32x4 part = *(const f32x4*)&Rq[(qg * 16 + c) * 64 + fd * 16 + 4 * g];
        f32x4 tot = (attT[fd][qg] + part) * inv[qg];
        int q = q0 + qh * 32 + qg * 16 + c;
        *(uint2*)(attbufb + ((size_t)bh * S_LEN + q) * DKH + fd * 16 + 4 * g) =
            make_uint2(pk_bf16(tot[0], tot[1]), pk_bf16(tot[2], tot[3]));
      }
  }
}

// ---------------- head-reduce + a@Wo_eff + bias + residual + LayerNorm ----------------
__global__ __launch_bounds__(256) void fuse_out_ln_k(const u16* __restrict__ attbufb,
    const float* __restrict__ Woeff, const float* __restrict__ bo,
    const float* __restrict__ x, const float* __restrict__ gamma,
    const float* __restrict__ beta, float* __restrict__ out) {
  __shared__ float red[8][256];
  __shared__ __align__(16) float a[8][64];
  __shared__ float sred[8][4][2];
  int t = threadIdx.x;
  int r0 = blockIdx.x * 8;
  int d = t & 63, hg = t >> 6;
#pragma unroll
  for (int rr = 0; rr < 8; ++rr) {
    int m = r0 + rr, b = m >> 11, sr = m & 2047;
    float pa = 0.f;
#pragma unroll
    for (int hh = 0; hh < 4; ++hh) {
      int h = hg * 4 + hh;
      pa += bf2f(attbufb[(((size_t)(b * 16 + h)) * S_LEN + sr) * DKH + d]);
    }
    red[rr][t] = pa;
  }
  __syncthreads();
#pragma unroll
  for (int e = 0; e < 2; ++e) {
    int idx = t + e * 256;
    int rr = idx >> 6, dd = idx & 63;
    a[rr][dd] = red[rr][dd] + red[rr][64 + dd] + red[rr][128 + dd] + red[rr][192 + dd];
  }
  __syncthreads();

  float o[8][4];
#pragma unroll
  for (int rr = 0; rr < 8; ++rr) { o[rr][0] = o[rr][1] = o[rr][2] = o[rr][3] = 0.f; }
  int c4 = t * 4;
  for (int dd = 0; dd < 64; dd += 4) {
    float4 wv0 = *(const float4*)(Woeff + (size_t)(dd + 0) * DMODEL + c4);
    float4 wv1 = *(const float4*)(Woeff + (size_t)(dd + 1) * DMODEL + c4);
    float4 wv2 = *(const float4*)(Woeff + (size_t)(dd + 2) * DMODEL + c4);
    float4 wv3 = *(const float4*)(Woeff + (size_t)(dd + 3) * DMODEL + c4);
#pragma unroll
    for (int rr = 0; rr < 8; ++rr) {
      float4 av = *(const float4*)&a[rr][dd];
      o[rr][0] += av.x * wv0.x + av.y * wv1.x + av.z * wv2.x + av.w * wv3.x;
      o[rr][1] += av.x * wv0.y + av.y * wv1.y + av.z * wv2.y + av.w * wv3.y;
      o[rr][2] += av.x * wv0.z + av.y * wv1.z + av.z * wv2.z + av.w * wv3.z;
      o[rr][3] += av.x * wv0.w + av.y * wv1.w + av.z * wv2.w + av.w * wv3.w;
    }
  }
  float4 bv = *(const float4*)(bo + c4);
  int w = t >> 6, lane = t & 63;
#pragma unroll
  for (int rr = 0; rr < 8; ++rr) {
    int m = r0 + rr;
    float4 xv = *(const float4*)(x + (size_t)m * DMODEL + c4);
    o[rr][0] += bv.x + xv.x;
    o[rr][1] += bv.y + xv.y;
    o[rr][2] += bv.z + xv.z;
    o[rr][3] += bv.w + xv.w;
    float s = o[rr][0] + o[rr][1] + o[rr][2] + o[rr][3];
    float q = o[rr][0] * o[rr][0] + o[rr][1] * o[rr][1] + o[rr][2] * o[rr][2] + o[rr][3] * o[rr][3];
#pragma unroll
    for (int mm = 1; mm < 64; mm <<= 1) {
      s += __shfl_xor(s, mm, 64);
      q += __shfl_xor(q, mm, 64);
    }
    if (lane == 0) { sred[rr][w][0] = s; sred[rr][w][1] = q; }
  }
  __syncthreads();
  float4 gv = *(const float4*)(gamma + c4);
  float4 bev = *(const float4*)(beta + c4);
#pragma unroll
  for (int rr = 0; rr < 8; ++rr) {
    float s = sred[rr][0][0] + sred[rr][1][0] + sred[rr][2][0] + sred[rr][3][0];
    float q = sred[rr][0][1] + sred[rr][1][1] + sred[rr][2][1] + sred[rr][3][1];
    float mu = s * (1.f / 1024.f);
    float var = q * (1.f / 1024.f) - mu * mu;
    float rs = rsqrtf(var + 1e-6f);
    int m = r0 + rr;
    float4 ov;
    ov.x = gv.x * (o[rr][0] - mu) * rs + bev.x;
    ov.y = gv.y * (o[rr][1] - mu) * rs + bev.y;
    ov.z = gv.z * (o[rr][2] - mu) * rs + bev.z;
    ov.w = gv.w * (o[rr][3] - mu) * rs + bev.w;
    *(float4*)(out + (size_t)m * DMODEL + c4) = ov;
  }
}

extern "C" void kernel_launch(void* const* d_in, const int* in_sizes, int n_in,
                              void* d_out, int out_size, void* d_ws, size_t ws_size,
                              hipStream_t stream) {
  const float* x = (const float*)d_in[0];
  const float* Wq = (const float*)d_in[1];
  const float* Wk = (const float*)d_in[2];
  const float* Wv = (const float*)d_in[3];
  const float* Wo = (const float*)d_in[4];
  const float* bo = (const float*)d_in[5];
  const float* ps = (const float*)d_in[6];
  const float* ent = (const float*)d_in[7];
  const float* gamma = (const float*)d_in[8];
  const float* beta = (const float*)d_in[9];
  float* out = (float*)d_out;

  char* ws = (char*)d_ws;
  size_t o = 0;
  u16* xb = (u16*)(ws + o);    o += (size_t)MROWS * DMODEL * 2;        // 8 MB
  u16* Wb = (u16*)(ws + o);    o += (size_t)3072 * 1024 * 2;           // 6 MB
  u16* Qb = (u16*)(ws + o);    o += (size_t)BH_CNT * S_LEN * DKH * 2;  // 8 MB
  u16* Kb = (u16*)(ws + o);    o += (size_t)BH_CNT * S_LEN * DKH * 2;  // 8 MB
  u16* Vt = (u16*)(ws + o);    o += (size_t)BH_CNT * S_LEN * DKH * 2;  // 8 MB
  float* Woeff = (float*)(ws + o);   o += (size_t)DKH * DMODEL * 4;    // 256 KB
  u16* attbufb = (u16*)(ws + o);     o += (size_t)BH_CNT * S_LEN * DKH * 2;  // 8 MB

  prep_all_k<<<dim3(7424), dim3(256), 0, stream>>>(x, Wq, Wk, Wv, Wo, ps, ent,
                                                   xb, Wb, Woeff);
  gemm_qkv_k<<<dim3(192), dim3(512), 0, stream>>>(xb, Wb, Qb, Kb, Vt);
  attn_k<<<dim3(512), dim3(512), 0, stream>>>(Qb, Kb, Vt, attbufb);
  fuse_out_ln_k<<<dim3(512), dim3(256), 0, stream>>>(attbufb, Woeff, bo, x, gamma, beta, out);
}